// Round 1
// baseline (646.066 us; speedup 1.0000x reference)
//
#include <hip/hip_runtime.h>
#include <math.h>

#define N_NODES 50000
#define N_EDGES 25000
#define MAX_ARITY 6
#define MAX_DEG 8
#define NFEAT 128
#define NHID 64
#define NEMB 128
#define NHEADS 4
#define BATCH 4096

__device__ __forceinline__ float wave_sum(float v) {
#pragma unroll
    for (int off = 1; off < 64; off <<= 1) v += __shfl_xor(v, off);
    return v;
}
__device__ __forceinline__ float lrelu(float x) { return x >= 0.f ? x : 0.2f * x; }
__device__ __forceinline__ float eluf(float x) { return x > 0.f ? x : expm1f(x); }

// ---------------------------------------------------------------------------
// f32 tiled GEMM: C(MxN) = A(MxK) @ B(KxN)
// HEADED_B: B is Wn/We with layout (4, NFEAT, NHID): B[h][k][j], col n = h*64+j
// ELU_A: apply elu() to A elements on load (for edge_out1 -> layer2 GEMM)
// ---------------------------------------------------------------------------
#define TBM 64
#define TBN 64
#define TBK 32

template <bool HEADED_B, bool ELU_A>
__global__ __launch_bounds__(256) void gemm_kernel(const float* __restrict__ A,
                                                   const float* __restrict__ B,
                                                   float* __restrict__ C,
                                                   int M, int N, int K) {
    __shared__ float As[TBK][TBM + 4];
    __shared__ float Bs[TBK][TBN + 4];
    const int bm = blockIdx.y * TBM;
    const int bn = blockIdx.x * TBN;
    const int tid = threadIdx.x;
    const int tx = tid & 15;   // 16 col-groups
    const int ty = tid >> 4;   // 16 row-groups
    float acc[4][4] = {{0.f, 0.f, 0.f, 0.f}};

    for (int k0 = 0; k0 < K; k0 += TBK) {
        // A tile: 64 rows x 32 k; consecutive tid -> consecutive k (coalesced)
#pragma unroll
        for (int i = 0; i < 8; ++i) {
            int idx = tid + i * 256;
            int r = idx >> 5, c = idx & 31;
            int m = bm + r;
            float v = 0.f;
            if (m < M) v = A[(size_t)m * K + (k0 + c)];
            if (ELU_A) v = eluf(v);
            As[c][r] = v;
        }
        // B tile: 32 k x 64 n; consecutive tid -> consecutive n (coalesced)
#pragma unroll
        for (int i = 0; i < 8; ++i) {
            int idx = tid + i * 256;
            int kk = idx >> 6, n = idx & 63;
            int gk = k0 + kk, gn = bn + n;
            float v;
            if (HEADED_B) {
                int h = gn >> 6, j = gn & 63;
                v = B[(h * NFEAT + gk) * NHID + j];
            } else {
                v = B[(size_t)gk * N + gn];
            }
            Bs[kk][n] = v;
        }
        __syncthreads();
#pragma unroll
        for (int kk = 0; kk < TBK; ++kk) {
            float4 a4 = *reinterpret_cast<const float4*>(&As[kk][ty * 4]);
            float4 b4 = *reinterpret_cast<const float4*>(&Bs[kk][tx * 4]);
            float a[4] = {a4.x, a4.y, a4.z, a4.w};
            float b[4] = {b4.x, b4.y, b4.z, b4.w};
#pragma unroll
            for (int i = 0; i < 4; ++i)
#pragma unroll
                for (int j = 0; j < 4; ++j) acc[i][j] = fmaf(a[i], b[j], acc[i][j]);
        }
        __syncthreads();
    }
#pragma unroll
    for (int i = 0; i < 4; ++i) {
        int m = bm + ty * 4 + i;
        if (m >= M) continue;
        float4 o = make_float4(acc[i][0], acc[i][1], acc[i][2], acc[i][3]);
        *reinterpret_cast<float4*>(&C[(size_t)m * N + bn + tx * 4]) = o;
    }
}

// ---------------------------------------------------------------------------
// Per-(row, head) 64-wide dot products against attention vectors (layer 1)
// X: (rows, 256) head-blocked. outA[row*4+h] = sum_j X[row,h*64+j]*vA[h*128+offA+j]
// ---------------------------------------------------------------------------
template <bool TWO>
__global__ __launch_bounds__(256) void rowdot64_kernel(const float* __restrict__ X, int rows,
                                                       const float* __restrict__ vA, int offA,
                                                       float* __restrict__ outA,
                                                       const float* __restrict__ vB, int offB,
                                                       float* __restrict__ outB) {
    int gw = blockIdx.x * 4 + (threadIdx.x >> 6);
    int lane = threadIdx.x & 63;
    if (gw >= rows * NHEADS) return;
    int row = gw >> 2, h = gw & 3;
    float x = X[(size_t)row * 256 + h * 64 + lane];
    float sA = wave_sum(x * vA[h * 128 + offA + lane]);
    if (TWO) {
        float sB = wave_sum(x * vB[h * 128 + offB + lane]);
        if (lane == 0) {
            outA[row * 4 + h] = sA;
            outB[row * 4 + h] = sB;
        }
    } else {
        if (lane == 0) outA[row * 4 + h] = sA;
    }
}

// Layer-2 variant: X: (rows, 128), single head, vectors are 256-long (off selects half)
template <bool TWO>
__global__ __launch_bounds__(256) void rowdot128_kernel(const float* __restrict__ X, int rows,
                                                        const float* __restrict__ vA, int offA,
                                                        float* __restrict__ outA,
                                                        const float* __restrict__ vB, int offB,
                                                        float* __restrict__ outB) {
    int gw = blockIdx.x * 4 + (threadIdx.x >> 6);
    int lane = threadIdx.x & 63;
    if (gw >= rows) return;
    float x0 = X[(size_t)gw * 128 + lane];
    float x1 = X[(size_t)gw * 128 + 64 + lane];
    float sA = wave_sum(x0 * vA[offA + lane] + x1 * vA[offA + 64 + lane]);
    if (TWO) {
        float sB = wave_sum(x0 * vB[offB + lane] + x1 * vB[offB + 64 + lane]);
        if (lane == 0) {
            outA[gw] = sA;
            outB[gw] = sB;
        }
    } else {
        if (lane == 0) outA[gw] = sA;
    }
}

// ---------------------------------------------------------------------------
// Layer-1 attention aggregate: wave per (row, head), lane = feature.
// score_a = lrelu(sdot[row,h] + ndot[nbr_a, h]); softmax over valid nbrs;
// outF[row, h*64+lane] = (elu?) sum_a att_a * feat[nbr_a, h*64+lane]
// DOT: outDot[row*4+h] = sum_lane out_pre_elu * fvec[h*128+64+lane]   (f1)
// ---------------------------------------------------------------------------
template <int NNBR, bool DOT, bool APPLY_ELU>
__global__ __launch_bounds__(256) void attn64_kernel(const int* __restrict__ nbr,
                                                     const float* __restrict__ feat,
                                                     const float* __restrict__ sdot,
                                                     const float* __restrict__ ndot,
                                                     const float* __restrict__ fvec,
                                                     float* __restrict__ outF,
                                                     float* __restrict__ outDot, int rows) {
    int gw = blockIdx.x * 4 + (threadIdx.x >> 6);
    int lane = threadIdx.x & 63;
    if (gw >= rows * NHEADS) return;
    int r = gw >> 2, h = gw & 3;
    float c = sdot[r * 4 + h];
    int id[NNBR];
    float w[NNBR];
    float smax = -1e30f;
#pragma unroll
    for (int a = 0; a < NNBR; ++a) {
        int v = nbr[r * NNBR + a];
        id[a] = (v > 0) ? (v - 1) : 0;
        if (v > 0) {
            float s = lrelu(c + ndot[(size_t)(v - 1) * 4 + h]);
            w[a] = s;
            smax = fmaxf(smax, s);
        } else {
            w[a] = -3e30f;
        }
    }
    float denom = 0.f;
#pragma unroll
    for (int a = 0; a < NNBR; ++a) {
        float ex = (w[a] > -1e30f) ? expf(w[a] - smax) : 0.f;
        w[a] = ex;
        denom += ex;
    }
    float inv = 1.f / denom;
    float acc = 0.f;
#pragma unroll
    for (int a = 0; a < NNBR; ++a)
        if (w[a] > 0.f) acc = fmaf(w[a], feat[(size_t)id[a] * 256 + h * 64 + lane], acc);
    acc *= inv;
    outF[(size_t)r * 256 + h * 64 + lane] = APPLY_ELU ? eluf(acc) : acc;
    if (DOT) {
        float t = wave_sum(acc * fvec[h * 128 + 64 + lane]);
        if (lane == 0) outDot[r * 4 + h] = t;
    }
}

// Layer-2 attention aggregate: wave per row, lane covers features lane & lane+64.
template <int NNBR, bool DOT>
__global__ __launch_bounds__(256) void attn128_kernel(const int* __restrict__ nbr,
                                                      const float* __restrict__ feat,
                                                      const float* __restrict__ sdot,
                                                      const float* __restrict__ ndot,
                                                      const float* __restrict__ fvec,
                                                      float* __restrict__ outF,
                                                      float* __restrict__ outDot, int rows) {
    int gw = blockIdx.x * 4 + (threadIdx.x >> 6);
    int lane = threadIdx.x & 63;
    if (gw >= rows) return;
    int r = gw;
    float c = sdot[r];
    int id[NNBR];
    float w[NNBR];
    float smax = -1e30f;
#pragma unroll
    for (int a = 0; a < NNBR; ++a) {
        int v = nbr[r * NNBR + a];
        id[a] = (v > 0) ? (v - 1) : 0;
        if (v > 0) {
            float s = lrelu(c + ndot[v - 1]);
            w[a] = s;
            smax = fmaxf(smax, s);
        } else {
            w[a] = -3e30f;
        }
    }
    float denom = 0.f;
#pragma unroll
    for (int a = 0; a < NNBR; ++a) {
        float ex = (w[a] > -1e30f) ? expf(w[a] - smax) : 0.f;
        w[a] = ex;
        denom += ex;
    }
    float inv = 1.f / denom;
    float acc0 = 0.f, acc1 = 0.f;
#pragma unroll
    for (int a = 0; a < NNBR; ++a) {
        if (w[a] > 0.f) {
            const float* p = feat + (size_t)id[a] * 128;
            acc0 = fmaf(w[a], p[lane], acc0);
            acc1 = fmaf(w[a], p[64 + lane], acc1);
        }
    }
    acc0 *= inv;
    acc1 *= inv;
    outF[(size_t)r * 128 + lane] = acc0;
    outF[(size_t)r * 128 + 64 + lane] = acc1;
    if (DOT) {
        float t = wave_sum(acc0 * fvec[128 + lane] + acc1 * fvec[192 + lane]);
        if (lane == 0) outDot[r] = t;
    }
}

// ---------------------------------------------------------------------------
// Batch gather: wave per (b, slot); lane covers features lane & lane+64.
// ---------------------------------------------------------------------------
__global__ __launch_bounds__(256) void batch_kernel(const int* __restrict__ bi,
                                                    const float* __restrict__ eo2,
                                                    const float* __restrict__ no2,
                                                    float* __restrict__ out) {
    int gw = blockIdx.x * 4 + (threadIdx.x >> 6);
    int lane = threadIdx.x & 63;
    if (gw >= BATCH * 7) return;
    int b = gw / 7, s = gw % 7;
    int last_nz = -1;
#pragma unroll
    for (int j = 0; j < 7; ++j)
        if (bi[b * 7 + j] != 0) last_nz = j;
    float v0, v1;
    if (s == 0) {
        int e = bi[b * 7] - 1;
        v0 = eluf(eo2[(size_t)e * 128 + lane]);
        v1 = eluf(eo2[(size_t)e * 128 + 64 + lane]);
    } else if (s <= last_nz) {
        int nid = bi[b * 7 + s] - 1;
        if (nid < 0) nid += N_NODES;
        v0 = eluf(no2[(size_t)nid * 128 + lane]);
        v1 = eluf(no2[(size_t)nid * 128 + 64 + lane]);
    } else {
        v0 = 1.f;
        v1 = 1.f;
    }
    out[(size_t)b * 896 + s * 128 + lane] = v0;
    out[(size_t)b * 896 + s * 128 + 64 + lane] = v1;
}

// ---------------------------------------------------------------------------
extern "C" void kernel_launch(void* const* d_in, const int* in_sizes, int n_in,
                              void* d_out, int out_size, void* d_ws, size_t ws_size,
                              hipStream_t stream) {
    const int* batch_inputs = (const int*)d_in[0];
    const int* edge_list = (const int*)d_in[1];
    const int* node_list = (const int*)d_in[2];
    const float* node_embs = (const float*)d_in[3];
    const float* edge_embs = (const float*)d_in[4];
    const float* Wn = (const float*)d_in[5];
    const float* We = (const float*)d_in[6];
    const float* a1 = (const float*)d_in[7];
    const float* a2 = (const float*)d_in[8];
    const float* Wn_o = (const float*)d_in[9];
    const float* We_o = (const float*)d_in[10];
    const float* a1_o = (const float*)d_in[11];
    const float* a2_o = (const float*)d_in[12];
    float* out = (float*)d_out;
    float* ws = (float*)d_ws;

    // workspace layout (floats); aliasing is sequenced safely:
    float* hn1 = ws + 0;         // 50000*256 = 12,800,000
    float* he1 = ws + 12800000;  // 25000*256 =  6,400,000
    float* eo1 = ws + 19200000;  //              6,400,000
    float* no1 = ws + 0;         // alias hn1 (hn1 dead after edge_attn1)
    float* hn2 = ws + 12800000;  // alias he1 (he1 dead after rowdots), 50000*128
    float* he2 = ws + 25600000;  // 25000*128 = 3,200,000
    float* eo2 = ws + 28800000;  //             3,200,000
    float* no2 = ws + 32000000;  // 50000*128 = 6,400,000
    float* d1 = ws + 38400000;   // 200,000
    float* g1v = ws + 38600000;  // 200,000
    float* c1 = ws + 38800000;   // 100,000
    float* f1 = ws + 38900000;   // 100,000
    float* d2 = ws + 39000000;   // 50,000
    float* g2v = ws + 39050000;  // 50,000
    float* c2 = ws + 39100000;   // 25,000
    float* f2 = ws + 39125000;   // 25,000
    // total: 39,150,000 floats = 156.6 MB

    // --- layer 1 GEMMs: hn1 = node_embs @ Wn (head-blocked), he1 = edge_embs @ We
    dim3 g1n(256 / TBN, (N_NODES + TBM - 1) / TBM);
    gemm_kernel<true, false><<<g1n, 256, 0, stream>>>(node_embs, Wn, hn1, N_NODES, 256, 128);
    dim3 g1e(256 / TBN, (N_EDGES + TBM - 1) / TBM);
    gemm_kernel<true, false><<<g1e, 256, 0, stream>>>(edge_embs, We, he1, N_EDGES, 256, 128);

    // --- layer 1 score dots: d1 = hn.a1[:,64:], g1 = hn.a2[:,:64], c1 = he.a1[:,:64]
    rowdot64_kernel<true><<<N_NODES, 256, 0, stream>>>(hn1, N_NODES, a1, 64, d1, a2, 0, g1v);
    rowdot64_kernel<false><<<N_EDGES, 256, 0, stream>>>(he1, N_EDGES, a1, 0, c1, nullptr, 0, nullptr);

    // --- layer 1 edge attention -> eo1 (pre-elu), f1 = eo1.a2[:,64:]
    attn64_kernel<MAX_ARITY, true, false><<<N_EDGES, 256, 0, stream>>>(
        edge_list, hn1, c1, d1, a2, eo1, f1, N_EDGES);
    // --- layer 1 node attention -> no1 (elu applied; feeds GEMM2 directly)
    attn64_kernel<MAX_DEG, false, true><<<N_NODES, 256, 0, stream>>>(
        node_list, eo1, g1v, f1, nullptr, no1, nullptr, N_NODES);

    // --- layer 2 GEMMs: hn2 = no1 @ Wn_o ; he2 = elu(eo1) @ We_o
    dim3 g2n(128 / TBN, (N_NODES + TBM - 1) / TBM);
    gemm_kernel<false, false><<<g2n, 256, 0, stream>>>(no1, Wn_o, hn2, N_NODES, 128, 256);
    dim3 g2e(128 / TBN, (N_EDGES + TBM - 1) / TBM);
    gemm_kernel<false, true><<<g2e, 256, 0, stream>>>(eo1, We_o, he2, N_EDGES, 128, 256);

    // --- layer 2 score dots
    rowdot128_kernel<true><<<(N_NODES + 3) / 4, 256, 0, stream>>>(hn2, N_NODES, a1_o, 128, d2,
                                                                  a2_o, 0, g2v);
    rowdot128_kernel<false><<<(N_EDGES + 3) / 4, 256, 0, stream>>>(he2, N_EDGES, a1_o, 0, c2,
                                                                   nullptr, 0, nullptr);

    // --- layer 2 edge attention -> eo2 (pre-elu), f2 = eo2.a2_o[128:]
    attn128_kernel<MAX_ARITY, true><<<(N_EDGES + 3) / 4, 256, 0, stream>>>(
        edge_list, hn2, c2, d2, a2_o, eo2, f2, N_EDGES);
    // --- layer 2 node attention -> no2 (pre-elu; elu applied in batch kernel)
    attn128_kernel<MAX_DEG, false><<<(N_NODES + 3) / 4, 256, 0, stream>>>(
        node_list, eo2, g2v, f2, nullptr, no2, nullptr, N_NODES);

    // --- batch gather
    batch_kernel<<<(BATCH * 7 + 3) / 4, 256, 0, stream>>>(batch_inputs, eo2, no2, out);
}

// Round 2
// 487.726 us; speedup vs baseline: 1.3246x; 1.3246x over previous
//
#include <hip/hip_runtime.h>
#include <math.h>

#define N_NODES 50000
#define N_EDGES 25000
#define MAX_ARITY 6
#define MAX_DEG 8
#define NFEAT 128
#define NHID 64
#define NEMB 128
#define NHEADS 4
#define BATCH 4096

__device__ __forceinline__ float wave_sum(float v) {
#pragma unroll
    for (int off = 1; off < 64; off <<= 1) v += __shfl_xor(v, off);
    return v;
}
__device__ __forceinline__ float group16_sum(float v) {
#pragma unroll
    for (int off = 1; off < 16; off <<= 1) v += __shfl_xor(v, off);
    return v;
}
__device__ __forceinline__ float lrelu(float x) { return x >= 0.f ? x : 0.2f * x; }
__device__ __forceinline__ float eluf(float x) { return x > 0.f ? x : expm1f(x); }

// ---------------------------------------------------------------------------
// f32 tiled GEMM: C(MxN) = A(MxK) @ B(KxN)
// HEADED_B: B is Wn/We with layout (4, NFEAT, NHID): B[h][k][j], col n = h*64+j
// ELU_A: apply elu() to A elements on load (for edge_out1 -> layer2 GEMM)
// NDOT: fused per-row dot products against vA/vB (layer-1 attention vectors).
//       Column block == one head (TBN=64), so dot over this block's 64 cols is
//       the full per-head dot: outA[m*4+h] = sum_j C[m, h*64+j] * vA[h*128+offA+j]
// ---------------------------------------------------------------------------
#define TBM 64
#define TBN 64
#define TBK 32

template <bool HEADED_B, bool ELU_A, int NDOT>
__global__ __launch_bounds__(256) void gemm_kernel(const float* __restrict__ A,
                                                   const float* __restrict__ B,
                                                   float* __restrict__ C,
                                                   int M, int N, int K,
                                                   const float* __restrict__ vA, int offA,
                                                   float* __restrict__ outA,
                                                   const float* __restrict__ vB, int offB,
                                                   float* __restrict__ outB) {
    __shared__ float As[TBK][TBM + 4];
    __shared__ float Bs[TBK][TBN + 4];
    const int bm = blockIdx.y * TBM;
    const int bn = blockIdx.x * TBN;
    const int tid = threadIdx.x;
    const int tx = tid & 15;   // 16 col-groups (consecutive lanes)
    const int ty = tid >> 4;   // 16 row-groups
    float acc[4][4] = {{0.f, 0.f, 0.f, 0.f}};

    for (int k0 = 0; k0 < K; k0 += TBK) {
#pragma unroll
        for (int i = 0; i < 8; ++i) {
            int idx = tid + i * 256;
            int r = idx >> 5, c = idx & 31;
            int m = bm + r;
            float v = 0.f;
            if (m < M) v = A[(size_t)m * K + (k0 + c)];
            if (ELU_A) v = eluf(v);
            As[c][r] = v;
        }
#pragma unroll
        for (int i = 0; i < 8; ++i) {
            int idx = tid + i * 256;
            int kk = idx >> 6, n = idx & 63;
            int gk = k0 + kk, gn = bn + n;
            float v;
            if (HEADED_B) {
                int h = gn >> 6, j = gn & 63;
                v = B[(h * NFEAT + gk) * NHID + j];
            } else {
                v = B[(size_t)gk * N + gn];
            }
            Bs[kk][n] = v;
        }
        __syncthreads();
#pragma unroll
        for (int kk = 0; kk < TBK; ++kk) {
            float4 a4 = *reinterpret_cast<const float4*>(&As[kk][ty * 4]);
            float4 b4 = *reinterpret_cast<const float4*>(&Bs[kk][tx * 4]);
            float a[4] = {a4.x, a4.y, a4.z, a4.w};
            float b[4] = {b4.x, b4.y, b4.z, b4.w};
#pragma unroll
            for (int i = 0; i < 4; ++i)
#pragma unroll
                for (int j = 0; j < 4; ++j) acc[i][j] = fmaf(a[i], b[j], acc[i][j]);
        }
        __syncthreads();
    }
#pragma unroll
    for (int i = 0; i < 4; ++i) {
        int m = bm + ty * 4 + i;
        if (m >= M) continue;
        float4 o = make_float4(acc[i][0], acc[i][1], acc[i][2], acc[i][3]);
        *reinterpret_cast<float4*>(&C[(size_t)m * N + bn + tx * 4]) = o;
    }
    if (NDOT >= 1) {
        // layer-1 only: HEADED, head h = bn>>6, local col j = tx*4+q
        const int h = bn >> 6;
        float va[4], vb[4];
#pragma unroll
        for (int q = 0; q < 4; ++q) {
            va[q] = vA[h * 128 + offA + tx * 4 + q];
            if (NDOT >= 2) vb[q] = vB[h * 128 + offB + tx * 4 + q];
        }
#pragma unroll
        for (int i = 0; i < 4; ++i) {
            float pA = acc[i][0] * va[0] + acc[i][1] * va[1] + acc[i][2] * va[2] +
                       acc[i][3] * va[3];
            pA = group16_sum(pA);
            float pB = 0.f;
            if (NDOT >= 2) {
                pB = acc[i][0] * vb[0] + acc[i][1] * vb[1] + acc[i][2] * vb[2] +
                     acc[i][3] * vb[3];
                pB = group16_sum(pB);
            }
            int m = bm + ty * 4 + i;
            if (tx == 0 && m < M) {
                outA[m * 4 + h] = pA;
                if (NDOT >= 2) outB[m * 4 + h] = pB;
            }
        }
    }
}

// ---------------------------------------------------------------------------
// Layer-2 row dots: X: (rows, 128), vectors are 256-long (off selects half)
// ---------------------------------------------------------------------------
template <bool TWO>
__global__ __launch_bounds__(256) void rowdot128_kernel(const float* __restrict__ X, int rows,
                                                        const float* __restrict__ vA, int offA,
                                                        float* __restrict__ outA,
                                                        const float* __restrict__ vB, int offB,
                                                        float* __restrict__ outB) {
    int gw = blockIdx.x * 4 + (threadIdx.x >> 6);
    int lane = threadIdx.x & 63;
    if (gw >= rows) return;
    float x0 = X[(size_t)gw * 128 + lane];
    float x1 = X[(size_t)gw * 128 + 64 + lane];
    float sA = wave_sum(x0 * vA[offA + lane] + x1 * vA[offA + 64 + lane]);
    if (TWO) {
        float sB = wave_sum(x0 * vB[offB + lane] + x1 * vB[offB + 64 + lane]);
        if (lane == 0) {
            outA[gw] = sA;
            outB[gw] = sB;
        }
    } else {
        if (lane == 0) outA[gw] = sA;
    }
}

// ---------------------------------------------------------------------------
// Layer-1 attention aggregate v2: ONE wave per row, all 4 heads.
// lane i owns features 4i..4i+3 (head h = lane>>4), gathers via float4.
// score_a = lrelu(sdot[row,h] + ndot[nbr_a,h]); per-head softmax; weighted sum.
// DOT: outDot[row*4+h] = sum_j out_pre_elu[h*64+j] * fvec[h*128+64+j]
// ---------------------------------------------------------------------------
template <int NNBR, bool DOT, bool APPLY_ELU>
__global__ __launch_bounds__(256) void attn64v2_kernel(const int* __restrict__ nbr,
                                                       const float* __restrict__ feat,
                                                       const float* __restrict__ sdot,
                                                       const float* __restrict__ ndot,
                                                       const float* __restrict__ fvec,
                                                       float* __restrict__ outF,
                                                       float* __restrict__ outDot, int rows) {
    int r = blockIdx.x * 4 + (threadIdx.x >> 6);
    int lane = threadIdx.x & 63;
    if (r >= rows) return;
    const int h = lane >> 4;
    const float c = sdot[r * 4 + h];
    int id[NNBR];
    float w[NNBR];
    float smax = -1e30f;
#pragma unroll
    for (int a = 0; a < NNBR; ++a) {
        int v = nbr[r * NNBR + a];
        id[a] = (v > 0) ? (v - 1) : 0;
        if (v > 0) {
            float s = lrelu(c + ndot[(size_t)id[a] * 4 + h]);
            w[a] = s;
            smax = fmaxf(smax, s);
        } else {
            w[a] = -3e30f;
        }
    }
    float denom = 0.f;
#pragma unroll
    for (int a = 0; a < NNBR; ++a) {
        float ex = (w[a] > -1e30f) ? expf(w[a] - smax) : 0.f;
        w[a] = ex;
        denom += ex;
    }
    float inv = 1.f / denom;
    float4 acc = make_float4(0.f, 0.f, 0.f, 0.f);
#pragma unroll
    for (int a = 0; a < NNBR; ++a) {
        if (w[a] > 0.f) {
            float4 f4 = *reinterpret_cast<const float4*>(feat + (size_t)id[a] * 256 + lane * 4);
            acc.x = fmaf(w[a], f4.x, acc.x);
            acc.y = fmaf(w[a], f4.y, acc.y);
            acc.z = fmaf(w[a], f4.z, acc.z);
            acc.w = fmaf(w[a], f4.w, acc.w);
        }
    }
    acc.x *= inv; acc.y *= inv; acc.z *= inv; acc.w *= inv;
    float4 o = acc;
    if (APPLY_ELU) { o.x = eluf(o.x); o.y = eluf(o.y); o.z = eluf(o.z); o.w = eluf(o.w); }
    *reinterpret_cast<float4*>(outF + (size_t)r * 256 + lane * 4) = o;
    if (DOT) {
        float4 fv = *reinterpret_cast<const float4*>(fvec + h * 128 + 64 + (lane & 15) * 4);
        float p = acc.x * fv.x + acc.y * fv.y + acc.z * fv.z + acc.w * fv.w;
        p = group16_sum(p);
        if ((lane & 15) == 0) outDot[r * 4 + h] = p;
    }
}

// Layer-2 attention aggregate: wave per row, lane covers features 2*lane, 2*lane+1.
template <int NNBR, bool DOT>
__global__ __launch_bounds__(256) void attn128_kernel(const int* __restrict__ nbr,
                                                      const float* __restrict__ feat,
                                                      const float* __restrict__ sdot,
                                                      const float* __restrict__ ndot,
                                                      const float* __restrict__ fvec,
                                                      float* __restrict__ outF,
                                                      float* __restrict__ outDot, int rows) {
    int r = blockIdx.x * 4 + (threadIdx.x >> 6);
    int lane = threadIdx.x & 63;
    if (r >= rows) return;
    float c = sdot[r];
    int id[NNBR];
    float w[NNBR];
    float smax = -1e30f;
#pragma unroll
    for (int a = 0; a < NNBR; ++a) {
        int v = nbr[r * NNBR + a];
        id[a] = (v > 0) ? (v - 1) : 0;
        if (v > 0) {
            float s = lrelu(c + ndot[v - 1]);
            w[a] = s;
            smax = fmaxf(smax, s);
        } else {
            w[a] = -3e30f;
        }
    }
    float denom = 0.f;
#pragma unroll
    for (int a = 0; a < NNBR; ++a) {
        float ex = (w[a] > -1e30f) ? expf(w[a] - smax) : 0.f;
        w[a] = ex;
        denom += ex;
    }
    float inv = 1.f / denom;
    float2 acc = make_float2(0.f, 0.f);
#pragma unroll
    for (int a = 0; a < NNBR; ++a) {
        if (w[a] > 0.f) {
            float2 f2 = *reinterpret_cast<const float2*>(feat + (size_t)id[a] * 128 + lane * 2);
            acc.x = fmaf(w[a], f2.x, acc.x);
            acc.y = fmaf(w[a], f2.y, acc.y);
        }
    }
    acc.x *= inv;
    acc.y *= inv;
    *reinterpret_cast<float2*>(outF + (size_t)r * 128 + lane * 2) = acc;
    if (DOT) {
        float t = wave_sum(acc.x * fvec[128 + lane * 2] + acc.y * fvec[128 + lane * 2 + 1]);
        if (lane == 0) outDot[r] = t;
    }
}

// ---------------------------------------------------------------------------
// Batch gather: wave per (b, slot); float2 per lane.
// ---------------------------------------------------------------------------
__global__ __launch_bounds__(256) void batch_kernel(const int* __restrict__ bi,
                                                    const float* __restrict__ eo2,
                                                    const float* __restrict__ no2,
                                                    float* __restrict__ out) {
    int gw = blockIdx.x * 4 + (threadIdx.x >> 6);
    int lane = threadIdx.x & 63;
    if (gw >= BATCH * 7) return;
    int b = gw / 7, s = gw % 7;
    int last_nz = -1;
#pragma unroll
    for (int j = 0; j < 7; ++j)
        if (bi[b * 7 + j] != 0) last_nz = j;
    float2 v;
    if (s == 0) {
        int e = bi[b * 7] - 1;
        float2 t = *reinterpret_cast<const float2*>(eo2 + (size_t)e * 128 + lane * 2);
        v = make_float2(eluf(t.x), eluf(t.y));
    } else if (s <= last_nz) {
        int nid = bi[b * 7 + s] - 1;
        if (nid < 0) nid += N_NODES;
        float2 t = *reinterpret_cast<const float2*>(no2 + (size_t)nid * 128 + lane * 2);
        v = make_float2(eluf(t.x), eluf(t.y));
    } else {
        v = make_float2(1.f, 1.f);
    }
    *reinterpret_cast<float2*>(out + (size_t)b * 896 + s * 128 + lane * 2) = v;
}

// ---------------------------------------------------------------------------
extern "C" void kernel_launch(void* const* d_in, const int* in_sizes, int n_in,
                              void* d_out, int out_size, void* d_ws, size_t ws_size,
                              hipStream_t stream) {
    const int* batch_inputs = (const int*)d_in[0];
    const int* edge_list = (const int*)d_in[1];
    const int* node_list = (const int*)d_in[2];
    const float* node_embs = (const float*)d_in[3];
    const float* edge_embs = (const float*)d_in[4];
    const float* Wn = (const float*)d_in[5];
    const float* We = (const float*)d_in[6];
    const float* a1 = (const float*)d_in[7];
    const float* a2 = (const float*)d_in[8];
    const float* Wn_o = (const float*)d_in[9];
    const float* We_o = (const float*)d_in[10];
    const float* a1_o = (const float*)d_in[11];
    const float* a2_o = (const float*)d_in[12];
    float* out = (float*)d_out;
    float* ws = (float*)d_ws;

    // workspace layout (floats); aliasing is sequenced safely:
    float* hn1 = ws + 0;         // 50000*256 = 12,800,000
    float* he1 = ws + 12800000;  // 25000*256 =  6,400,000
    float* eo1 = ws + 19200000;  //              6,400,000
    float* no1 = ws + 0;         // alias hn1 (hn1 dead after edge_attn1)
    float* hn2 = ws + 12800000;  // alias he1 (he1 dead after GEMM1), 50000*128
    float* he2 = ws + 25600000;  // 25000*128 = 3,200,000
    float* eo2 = ws + 28800000;  //             3,200,000
    float* no2 = ws + 32000000;  // 50000*128 = 6,400,000
    float* d1 = ws + 38400000;   // 200,000
    float* g1v = ws + 38600000;  // 200,000
    float* c1 = ws + 38800000;   // 100,000
    float* f1 = ws + 38900000;   // 100,000
    float* d2 = ws + 39000000;   // 50,000
    float* g2v = ws + 39050000;  // 50,000
    float* c2 = ws + 39100000;   // 25,000
    float* f2 = ws + 39125000;   // 25,000
    // total: 39,150,000 floats = 156.6 MB

    // --- layer 1 GEMMs with fused attention-vector dots:
    // hn1 = node_embs @ Wn ; d1 = hn1 . a1[:,64:] ; g1v = hn1 . a2[:,:64]
    dim3 g1n(256 / TBN, (N_NODES + TBM - 1) / TBM);
    gemm_kernel<true, false, 2><<<g1n, 256, 0, stream>>>(node_embs, Wn, hn1, N_NODES, 256, 128,
                                                         a1, 64, d1, a2, 0, g1v);
    // he1 = edge_embs @ We ; c1 = he1 . a1[:,:64]
    dim3 g1e(256 / TBN, (N_EDGES + TBM - 1) / TBM);
    gemm_kernel<true, false, 1><<<g1e, 256, 0, stream>>>(edge_embs, We, he1, N_EDGES, 256, 128,
                                                         a1, 0, c1, nullptr, 0, nullptr);

    // --- layer 1 edge attention -> eo1 (pre-elu), f1 = eo1 . a2[:,64:]
    attn64v2_kernel<MAX_ARITY, true, false><<<(N_EDGES + 3) / 4, 256, 0, stream>>>(
        edge_list, hn1, c1, d1, a2, eo1, f1, N_EDGES);
    // --- layer 1 node attention -> no1 (elu applied; feeds GEMM2 directly)
    attn64v2_kernel<MAX_DEG, false, true><<<(N_NODES + 3) / 4, 256, 0, stream>>>(
        node_list, eo1, g1v, f1, nullptr, no1, nullptr, N_NODES);

    // --- layer 2 GEMMs: hn2 = no1 @ Wn_o ; he2 = elu(eo1) @ We_o
    dim3 g2n(128 / TBN, (N_NODES + TBM - 1) / TBM);
    gemm_kernel<false, false, 0><<<g2n, 256, 0, stream>>>(no1, Wn_o, hn2, N_NODES, 128, 256,
                                                          nullptr, 0, nullptr, nullptr, 0, nullptr);
    dim3 g2e(128 / TBN, (N_EDGES + TBM - 1) / TBM);
    gemm_kernel<false, true, 0><<<g2e, 256, 0, stream>>>(eo1, We_o, he2, N_EDGES, 128, 256,
                                                         nullptr, 0, nullptr, nullptr, 0, nullptr);

    // --- layer 2 score dots
    rowdot128_kernel<true><<<(N_NODES + 3) / 4, 256, 0, stream>>>(hn2, N_NODES, a1_o, 128, d2,
                                                                  a2_o, 0, g2v);
    rowdot128_kernel<false><<<(N_EDGES + 3) / 4, 256, 0, stream>>>(he2, N_EDGES, a1_o, 0, c2,
                                                                   nullptr, 0, nullptr);

    // --- layer 2 edge attention -> eo2 (pre-elu), f2 = eo2 . a2_o[128:]
    attn128_kernel<MAX_ARITY, true><<<(N_EDGES + 3) / 4, 256, 0, stream>>>(
        edge_list, hn2, c2, d2, a2_o, eo2, f2, N_EDGES);
    // --- layer 2 node attention -> no2 (pre-elu; elu applied in batch kernel)
    attn128_kernel<MAX_DEG, false><<<(N_NODES + 3) / 4, 256, 0, stream>>>(
        node_list, eo2, g2v, f2, nullptr, no2, nullptr, N_NODES);

    // --- batch gather
    batch_kernel<<<(BATCH * 7 + 3) / 4, 256, 0, stream>>>(batch_inputs, eo2, no2, out);
}

// Round 3
// 321.849 us; speedup vs baseline: 2.0074x; 1.5154x over previous
//
#include <hip/hip_runtime.h>
#include <math.h>

#define N_NODES 50000
#define N_EDGES 25000
#define MAX_ARITY 6
#define MAX_DEG 8
#define NFEAT 128
#define NHID 64
#define NEMB 128
#define NHEADS 4
#define BATCH 4096

// padded m-tile counts (16 rows per tile, 8 tiles per GEMM block)
#define MT_N 3128   // ceil(50000/128)*8 -> rows padded to 50048
#define MT_E 1568   // ceil(25000/128)*8 -> rows padded to 25088

typedef __bf16 bf16x8 __attribute__((ext_vector_type(8)));
typedef __bf16 bf16x4 __attribute__((ext_vector_type(4)));
typedef float f32x4 __attribute__((ext_vector_type(4)));

__device__ __forceinline__ float wave_sum(float v) {
#pragma unroll
    for (int off = 1; off < 64; off <<= 1) v += __shfl_xor(v, off);
    return v;
}
__device__ __forceinline__ float group16_sum(float v) {
#pragma unroll
    for (int off = 1; off < 16; off <<= 1) v += __shfl_xor(v, off);
    return v;
}
__device__ __forceinline__ float lrelu(float x) { return x >= 0.f ? x : 0.2f * x; }
__device__ __forceinline__ float eluf(float x) { return x > 0.f ? x : expm1f(x); }

// ---------------------------------------------------------------------------
// repack: f32 row-major (M x K) -> bf16 MFMA A-fragment order
// dst[mt][kt][lane][8]: row = mt*16+(lane&15), k = kt*32+(lane>>4)*8+j
// rows >= M are zero-filled (covers padding; ws is poisoned otherwise).
// ---------------------------------------------------------------------------
__global__ __launch_bounds__(256) void repack_kernel(const float* __restrict__ src,
                                                     __bf16* __restrict__ dst, int M, int K,
                                                     int KT, int total) {
    int t = blockIdx.x * 256 + threadIdx.x;
    if (t >= total) return;
    int lane = t & 63;
    int kt = (t >> 6) % KT;
    int mt = t / (64 * KT);
    int row = mt * 16 + (lane & 15);
    int ks = kt * 32 + (lane >> 4) * 8;
    float v[8];
    if (row < M) {
        float4 p0 = *reinterpret_cast<const float4*>(src + (size_t)row * K + ks);
        float4 p1 = *reinterpret_cast<const float4*>(src + (size_t)row * K + ks + 4);
        v[0] = p0.x; v[1] = p0.y; v[2] = p0.z; v[3] = p0.w;
        v[4] = p1.x; v[5] = p1.y; v[6] = p1.z; v[7] = p1.w;
    } else {
#pragma unroll
        for (int j = 0; j < 8; ++j) v[j] = 0.f;
    }
    bf16x8 o;
#pragma unroll
    for (int j = 0; j < 8; ++j) o[j] = (__bf16)v[j];
    reinterpret_cast<bf16x8*>(dst)[t] = o;
}

// ---------------------------------------------------------------------------
// bconv: weights f32 -> bf16 B-fragment order
// dst[kt][nt][lane][8]: col n = nt*16+(lane&15), k = kt*32+(lane>>4)*8+j
// HEADED: src = Wn/We (4,128,64), global col = h*64 + nloc  (h = nt>>2)
// flat:   src = (K x N) row-major, N = 128
// ---------------------------------------------------------------------------
template <bool HEADED>
__global__ __launch_bounds__(256) void bconv_kernel(const float* __restrict__ src,
                                                    __bf16* __restrict__ dst, int KT, int NT,
                                                    int N) {
    int t = blockIdx.x * 256 + threadIdx.x;
    if (t >= KT * NT * 64) return;
    int lane = t & 63;
    int nt = (t >> 6) % NT;
    int kt = t / (64 * NT);
    int k0 = kt * 32 + (lane >> 4) * 8;
    bf16x8 o;
#pragma unroll
    for (int j = 0; j < 8; ++j) {
        int k = k0 + j;
        float v;
        if (HEADED) {
            int h = nt >> 2;
            int nl = (nt & 3) * 16 + (lane & 15);
            v = src[(h * NFEAT + k) * NHID + nl];
        } else {
            int n = nt * 16 + (lane & 15);
            v = src[(size_t)k * N + n];
        }
        o[j] = (__bf16)v;
    }
    reinterpret_cast<bf16x8*>(dst)[t] = o;
}

// ---------------------------------------------------------------------------
// wc1[h][k] = sum_j We[h][k][j]*a1[h][j] (j<64) ; wc2[k] = sum_j We_o[k][j]*a1_o[j]
// (associativity: he is only used through these dots -> he GEMMs eliminated)
// ---------------------------------------------------------------------------
__global__ void wvec1_kernel(const float* __restrict__ We, const float* __restrict__ a1,
                             float* __restrict__ wc1) {
    int t = blockIdx.x * 256 + threadIdx.x;
    if (t >= 512) return;
    int h = t >> 7, k = t & 127;
    float s = 0.f;
    for (int j = 0; j < 64; ++j) s += We[(h * NFEAT + k) * NHID + j] * a1[h * 128 + j];
    wc1[t] = s;
}
__global__ void wvec2_kernel(const float* __restrict__ Weo, const float* __restrict__ a1o,
                             float* __restrict__ wc2) {
    int t = blockIdx.x * 256 + threadIdx.x;
    if (t >= 256) return;
    float s = 0.f;
    for (int j = 0; j < 128; ++j) s += Weo[(size_t)t * 128 + j] * a1o[j];
    wc2[t] = s;
}

// c1[m][h] = sum_k edge_embs[m][k] * wc1[h][k]
__global__ __launch_bounds__(256) void c1_kernel(const float* __restrict__ X,
                                                 const float* __restrict__ wc1,
                                                 float* __restrict__ c1, int rows) {
    int r = blockIdx.x * 4 + (threadIdx.x >> 6);
    int lane = threadIdx.x & 63;
    if (r >= rows) return;
    float x0 = X[(size_t)r * 128 + lane];
    float x1 = X[(size_t)r * 128 + 64 + lane];
#pragma unroll
    for (int h = 0; h < 4; ++h) {
        float s = wave_sum(x0 * wc1[h * 128 + lane] + x1 * wc1[h * 128 + 64 + lane]);
        if (lane == 0) c1[r * 4 + h] = s;
    }
}

// ---------------------------------------------------------------------------
// LDS-free MFMA GEMM. A: bf16 frag order [mt][KT][64][8]; B: [kt][NTB][64][8].
// Block: 256 thr = 4 waves; 8 m-tiles/block (2 per wave); BNF n-frags.
// DOTMODE 1: layer-1 (BN=64=one head, out[m*4+h]); 2: layer-2 (BN=128, out[m]).
// ---------------------------------------------------------------------------
template <int KT, int BNF, int DOTMODE, int NDOTV>
__global__ __launch_bounds__(256) void mgemm_kernel(
    const __bf16* __restrict__ A, const __bf16* __restrict__ B, float* __restrict__ C, int M,
    int N, int NTB, const float* __restrict__ vA, int offA, float* __restrict__ outA,
    const float* __restrict__ vB, int offB, float* __restrict__ outB) {
    const int w = threadIdx.x >> 6, l = threadIdx.x & 63;
    const int mtb = blockIdx.y * 8 + w * 2;
    const int nbf = blockIdx.x * BNF;
    f32x4 acc[2][BNF];
#pragma unroll
    for (int i = 0; i < 2; ++i)
#pragma unroll
        for (int j = 0; j < BNF; ++j) acc[i][j] = (f32x4){0.f, 0.f, 0.f, 0.f};
    const bf16x8* A0 = reinterpret_cast<const bf16x8*>(A) + (size_t)mtb * KT * 64 + l;
    const bf16x8* A1 = A0 + KT * 64;
    const bf16x8* Bp = reinterpret_cast<const bf16x8*>(B) + l;
#pragma unroll
    for (int kt = 0; kt < KT; ++kt) {
        bf16x8 a0 = A0[kt * 64];
        bf16x8 a1 = A1[kt * 64];
#pragma unroll
        for (int nj = 0; nj < BNF; ++nj) {
            bf16x8 b = Bp[((size_t)kt * NTB + nbf + nj) * 64];
            acc[0][nj] = __builtin_amdgcn_mfma_f32_16x16x32_bf16(a0, b, acc[0][nj], 0, 0, 0);
            acc[1][nj] = __builtin_amdgcn_mfma_f32_16x16x32_bf16(a1, b, acc[1][nj], 0, 0, 0);
        }
    }
    const int rq = (l >> 4) * 4;
    const int cl = l & 15;
    // C write: row m = (mtb+mi)*16 + rq + q, col = (nbf+nj)*16 + cl
#pragma unroll
    for (int mi = 0; mi < 2; ++mi) {
        int mbase = (mtb + mi) * 16 + rq;
#pragma unroll
        for (int q = 0; q < 4; ++q) {
            int m = mbase + q;
            if (m < M) {
#pragma unroll
                for (int nj = 0; nj < BNF; ++nj)
                    C[(size_t)m * N + (nbf + nj) * 16 + cl] = acc[mi][nj][q];
            }
        }
    }
    if (DOTMODE) {
        float va[BNF], vb[BNF];
        const int vbase = (DOTMODE == 1) ? (nbf >> 2) * 128 : 0;
#pragma unroll
        for (int nj = 0; nj < BNF; ++nj) {
            int col = (DOTMODE == 1) ? ((nbf + nj) & 3) * 16 + cl : (nbf + nj) * 16 + cl;
            va[nj] = vA[vbase + offA + col];
            if (NDOTV >= 2) vb[nj] = vB[vbase + offB + col];
        }
        const int outStride = (DOTMODE == 1) ? 4 : 1;
        const int outOff = (DOTMODE == 1) ? (nbf >> 2) : 0;
#pragma unroll
        for (int mi = 0; mi < 2; ++mi) {
#pragma unroll
            for (int q = 0; q < 4; ++q) {
                float pA = 0.f, pB = 0.f;
#pragma unroll
                for (int nj = 0; nj < BNF; ++nj) {
                    pA += acc[mi][nj][q] * va[nj];
                    if (NDOTV >= 2) pB += acc[mi][nj][q] * vb[nj];
                }
                pA = group16_sum(pA);
                if (NDOTV >= 2) pB = group16_sum(pB);
                int m = (mtb + mi) * 16 + rq + q;
                if (cl == 0 && m < M) {
                    outA[(size_t)m * outStride + outOff] = pA;
                    if (NDOTV >= 2) outB[(size_t)m * outStride + outOff] = pB;
                }
            }
        }
    }
}

// ---------------------------------------------------------------------------
// Layer-1 EDGE attention: wave per edge, lane owns features 4l..4l+3 (head l>>4).
// outputs: eo1 f32 (pre-elu), f1 = eo1_pre . a2[h,64:], c2 = elu(eo1) . wc2
// ---------------------------------------------------------------------------
__global__ __launch_bounds__(256) void attn64e_kernel(
    const int* __restrict__ nbr, const float* __restrict__ feat, const float* __restrict__ sdot,
    const float* __restrict__ ndot, const float* __restrict__ a2v, const float* __restrict__ wc2,
    float* __restrict__ eo1, float* __restrict__ f1, float* __restrict__ c2, int rows) {
    int r = blockIdx.x * 4 + (threadIdx.x >> 6);
    int lane = threadIdx.x & 63;
    if (r >= rows) return;
    const int h = lane >> 4;
    const float c = sdot[r * 4 + h];
    int id[MAX_ARITY];
    float wgt[MAX_ARITY];
    float smax = -1e30f;
#pragma unroll
    for (int a = 0; a < MAX_ARITY; ++a) {
        int v = nbr[r * MAX_ARITY + a];
        id[a] = (v > 0) ? (v - 1) : 0;
        if (v > 0) {
            float s = lrelu(c + ndot[(size_t)id[a] * 4 + h]);
            wgt[a] = s;
            smax = fmaxf(smax, s);
        } else {
            wgt[a] = -3e30f;
        }
    }
    float denom = 0.f;
#pragma unroll
    for (int a = 0; a < MAX_ARITY; ++a) {
        float ex = (wgt[a] > -1e30f) ? expf(wgt[a] - smax) : 0.f;
        wgt[a] = ex;
        denom += ex;
    }
    float inv = 1.f / denom;
    float4 acc = make_float4(0.f, 0.f, 0.f, 0.f);
#pragma unroll
    for (int a = 0; a < MAX_ARITY; ++a) {
        if (wgt[a] > 0.f) {
            float4 f4 = *reinterpret_cast<const float4*>(feat + (size_t)id[a] * 256 + lane * 4);
            acc.x = fmaf(wgt[a], f4.x, acc.x);
            acc.y = fmaf(wgt[a], f4.y, acc.y);
            acc.z = fmaf(wgt[a], f4.z, acc.z);
            acc.w = fmaf(wgt[a], f4.w, acc.w);
        }
    }
    acc.x *= inv; acc.y *= inv; acc.z *= inv; acc.w *= inv;
    *reinterpret_cast<float4*>(eo1 + (size_t)r * 256 + lane * 4) = acc;
    // f1: per-head dot with a2[h, 64:128] on pre-elu values
    float4 fv = *reinterpret_cast<const float4*>(a2v + h * 128 + 64 + (lane & 15) * 4);
    float p = acc.x * fv.x + acc.y * fv.y + acc.z * fv.z + acc.w * fv.w;
    p = group16_sum(p);
    if ((lane & 15) == 0) f1[r * 4 + h] = p;
    // c2: full-row dot of elu(eo1) with wc2
    float4 e = make_float4(eluf(acc.x), eluf(acc.y), eluf(acc.z), eluf(acc.w));
    float4 w2 = *reinterpret_cast<const float4*>(wc2 + lane * 4);
    float p2 = wave_sum(e.x * w2.x + e.y * w2.y + e.z * w2.z + e.w * w2.w);
    if (lane == 0) c2[r] = p2;
}

// ---------------------------------------------------------------------------
// Layer-1 NODE attention: wave per node; writes elu(out) DIRECTLY as bf16
// A-fragments for GEMM2 (KT=8). Pad rows (>= rows) write zero frags.
// frag dest for feature f of row r: kt=f>>5, g=(f>>3)&3, j=f&7,
//   dst = ((mt*8+kt)*64 + g*16 + rr)*8 + j   (lane l owns f=4l..4l+3)
// ---------------------------------------------------------------------------
__global__ __launch_bounds__(256) void attn64n_kernel(const int* __restrict__ nbr,
                                                      const float* __restrict__ feat,
                                                      const float* __restrict__ sdot,
                                                      const float* __restrict__ ndot,
                                                      __bf16* __restrict__ Afrag, int rows,
                                                      int rowsPad) {
    int r = blockIdx.x * 4 + (threadIdx.x >> 6);
    int lane = threadIdx.x & 63;
    if (r >= rowsPad) return;
    const int rr = r & 15, mt = r >> 4;
    const int kt = lane >> 3, g = (lane >> 1) & 3, sub = lane & 1;
    __bf16* dptr = Afrag + ((((size_t)mt * 8 + kt) * 64 + g * 16 + rr) << 3) + sub * 4;
    if (r >= rows) {
        bf16x4 z = {(__bf16)0.f, (__bf16)0.f, (__bf16)0.f, (__bf16)0.f};
        *reinterpret_cast<bf16x4*>(dptr) = z;
        return;
    }
    const int h = lane >> 4;
    const float c = sdot[r * 4 + h];
    int id[MAX_DEG];
    float wgt[MAX_DEG];
    float smax = -1e30f;
#pragma unroll
    for (int a = 0; a < MAX_DEG; ++a) {
        int v = nbr[r * MAX_DEG + a];
        id[a] = (v > 0) ? (v - 1) : 0;
        if (v > 0) {
            float s = lrelu(c + ndot[(size_t)id[a] * 4 + h]);
            wgt[a] = s;
            smax = fmaxf(smax, s);
        } else {
            wgt[a] = -3e30f;
        }
    }
    float denom = 0.f;
#pragma unroll
    for (int a = 0; a < MAX_DEG; ++a) {
        float ex = (wgt[a] > -1e30f) ? expf(wgt[a] - smax) : 0.f;
        wgt[a] = ex;
        denom += ex;
    }
    float inv = 1.f / denom;
    float4 acc = make_float4(0.f, 0.f, 0.f, 0.f);
#pragma unroll
    for (int a = 0; a < MAX_DEG; ++a) {
        if (wgt[a] > 0.f) {
            float4 f4 = *reinterpret_cast<const float4*>(feat + (size_t)id[a] * 256 + lane * 4);
            acc.x = fmaf(wgt[a], f4.x, acc.x);
            acc.y = fmaf(wgt[a], f4.y, acc.y);
            acc.z = fmaf(wgt[a], f4.z, acc.z);
            acc.w = fmaf(wgt[a], f4.w, acc.w);
        }
    }
    bf16x4 o = {(__bf16)eluf(acc.x * inv), (__bf16)eluf(acc.y * inv), (__bf16)eluf(acc.z * inv),
                (__bf16)eluf(acc.w * inv)};
    *reinterpret_cast<bf16x4*>(dptr) = o;
}

// ---------------------------------------------------------------------------
// Layer-2 attention (unchanged structure): wave per row, float2 per lane.
// ---------------------------------------------------------------------------
template <int NNBR, bool DOT>
__global__ __launch_bounds__(256) void attn128_kernel(const int* __restrict__ nbr,
                                                      const float* __restrict__ feat,
                                                      const float* __restrict__ sdot,
                                                      const float* __restrict__ ndot,
                                                      const float* __restrict__ fvec,
                                                      float* __restrict__ outF,
                                                      float* __restrict__ outDot, int rows) {
    int r = blockIdx.x * 4 + (threadIdx.x >> 6);
    int lane = threadIdx.x & 63;
    if (r >= rows) return;
    float c = sdot[r];
    int id[NNBR];
    float wgt[NNBR];
    float smax = -1e30f;
#pragma unroll
    for (int a = 0; a < NNBR; ++a) {
        int v = nbr[r * NNBR + a];
        id[a] = (v > 0) ? (v - 1) : 0;
        if (v > 0) {
            float s = lrelu(c + ndot[v - 1]);
            wgt[a] = s;
            smax = fmaxf(smax, s);
        } else {
            wgt[a] = -3e30f;
        }
    }
    float denom = 0.f;
#pragma unroll
    for (int a = 0; a < NNBR; ++a) {
        float ex = (wgt[a] > -1e30f) ? expf(wgt[a] - smax) : 0.f;
        wgt[a] = ex;
        denom += ex;
    }
    float inv = 1.f / denom;
    float2 acc = make_float2(0.f, 0.f);
#pragma unroll
    for (int a = 0; a < NNBR; ++a) {
        if (wgt[a] > 0.f) {
            float2 f2 = *reinterpret_cast<const float2*>(feat + (size_t)id[a] * 128 + lane * 2);
            acc.x = fmaf(wgt[a], f2.x, acc.x);
            acc.y = fmaf(wgt[a], f2.y, acc.y);
        }
    }
    acc.x *= inv;
    acc.y *= inv;
    *reinterpret_cast<float2*>(outF + (size_t)r * 128 + lane * 2) = acc;
    if (DOT) {
        float t = wave_sum(acc.x * fvec[128 + lane * 2] + acc.y * fvec[128 + lane * 2 + 1]);
        if (lane == 0) outDot[r] = t;
    }
}

// ---------------------------------------------------------------------------
__global__ __launch_bounds__(256) void batch_kernel(const int* __restrict__ bi,
                                                    const float* __restrict__ eo2,
                                                    const float* __restrict__ no2,
                                                    float* __restrict__ out) {
    int gw = blockIdx.x * 4 + (threadIdx.x >> 6);
    int lane = threadIdx.x & 63;
    if (gw >= BATCH * 7) return;
    int b = gw / 7, s = gw % 7;
    int last_nz = -1;
#pragma unroll
    for (int j = 0; j < 7; ++j)
        if (bi[b * 7 + j] != 0) last_nz = j;
    float2 v;
    if (s == 0) {
        int e = bi[b * 7] - 1;
        float2 t = *reinterpret_cast<const float2*>(eo2 + (size_t)e * 128 + lane * 2);
        v = make_float2(eluf(t.x), eluf(t.y));
    } else if (s <= last_nz) {
        int nid = bi[b * 7 + s] - 1;
        if (nid < 0) nid += N_NODES;
        float2 t = *reinterpret_cast<const float2*>(no2 + (size_t)nid * 128 + lane * 2);
        v = make_float2(eluf(t.x), eluf(t.y));
    } else {
        v = make_float2(1.f, 1.f);
    }
    *reinterpret_cast<float2*>(out + (size_t)b * 896 + s * 128 + lane * 2) = v;
}

// ---------------------------------------------------------------------------
extern "C" void kernel_launch(void* const* d_in, const int* in_sizes, int n_in,
                              void* d_out, int out_size, void* d_ws, size_t ws_size,
                              hipStream_t stream) {
    const int* batch_inputs = (const int*)d_in[0];
    const int* edge_list = (const int*)d_in[1];
    const int* node_list = (const int*)d_in[2];
    const float* node_embs = (const float*)d_in[3];
    const float* edge_embs = (const float*)d_in[4];
    const float* Wn = (const float*)d_in[5];
    const float* We = (const float*)d_in[6];
    const float* a1 = (const float*)d_in[7];
    const float* a2 = (const float*)d_in[8];
    const float* Wn_o = (const float*)d_in[9];
    const float* We_o = (const float*)d_in[10];
    const float* a1_o = (const float*)d_in[11];
    const float* a2_o = (const float*)d_in[12];
    float* out = (float*)d_out;
    char* ws = (char*)d_ws;

    // ---- workspace layout (bytes) ----
    __bf16* A1n = (__bf16*)(ws);                    // MT_N*4*512*2 = 12,812,288
    __bf16* B1n = (__bf16*)(ws + 12812288);         // 65,536
    __bf16* B2n = (__bf16*)(ws + 12877824);         // 65,536
    float* wc1 = (float*)(ws + 12943360);           // 2,048
    float* wc2 = (float*)(ws + 12945408);           // 1,024
    float* c1 = (float*)(ws + 12946432);            // 400,000
    float* d1 = (float*)(ws + 13346432);            // 800,000
    float* g1v = (float*)(ws + 14146432);           // 800,000
    float* f1 = (float*)(ws + 14946432);            // 400,000
    float* c2 = (float*)(ws + 15346432);            // 100,000
    float* d2 = (float*)(ws + 15446432);            // 200,000
    float* g2v = (float*)(ws + 15646432);           // 200,000
    float* f2 = (float*)(ws + 15846432);            // 100,000
    float* hn1 = (float*)(ws + 16000000);           // 51,200,000 (dead after attn64e)
    // A2n and hn2 overlay the dead hn1 region:
    __bf16* A2n = (__bf16*)(ws + 16000000);         // MT_N*8*512*2 = 25,624,576
    float* hn2 = (float*)(ws + 16000000 + 25624576); // 25,600,000
    float* eo1 = (float*)(ws + 68000000);           // 25,600,000 (dead after attn64n)
    float* no2 = (float*)(ws + 68000000);           // 25,600,000 (overlays dead eo1)
    float* eo2 = (float*)(ws + 93600000);           // 12,800,000
    // total: ~106.4 MB

    // 1) repack node_embs -> A1n (bf16 frag order, padded to MT_N tiles)
    {
        int total = MT_N * 4 * 64;
        repack_kernel<<<(total + 255) / 256, 256, 0, stream>>>(node_embs, A1n, N_NODES, 128, 4,
                                                               total);
    }
    // 2) weight conversions
    bconv_kernel<true><<<16, 256, 0, stream>>>(Wn, B1n, 4, 16, 64);
    bconv_kernel<false><<<16, 256, 0, stream>>>(Wn_o, B2n, 8, 8, 128);
    // 3) he-elimination vectors + c1 matvec
    wvec1_kernel<<<2, 256, 0, stream>>>(We, a1, wc1);
    wvec2_kernel<<<1, 256, 0, stream>>>(We_o, a1_o, wc2);
    c1_kernel<<<(N_EDGES + 3) / 4, 256, 0, stream>>>(edge_embs, wc1, c1, N_EDGES);

    // 4) G1n: hn1 = node_embs @ Wn  (+ d1 = hn1.a1[:,64:], g1v = hn1.a2[:,:64])
    {
        dim3 g(4, MT_N / 8);
        mgemm_kernel<4, 4, 1, 2><<<g, 256, 0, stream>>>(A1n, B1n, hn1, N_NODES, 256, 16, a1, 64,
                                                        d1, a2, 0, g1v);
    }
    // 5) layer-1 edge attention -> eo1 (pre-elu), f1, c2
    attn64e_kernel<<<(N_EDGES + 3) / 4, 256, 0, stream>>>(edge_list, hn1, c1, d1, a2, wc2, eo1,
                                                          f1, c2, N_EDGES);
    // 6) layer-1 node attention -> A2n (elu'd bf16 frags, padded)
    attn64n_kernel<<<(MT_N * 16 + 3) / 4, 256, 0, stream>>>(node_list, eo1, g1v, f1, A2n,
                                                            N_NODES, MT_N * 16);
    // 7) G2n: hn2 = no1 @ Wn_o (+ d2 = hn2.a1_o[128:], g2v = hn2.a2_o[:128])
    {
        dim3 g(1, MT_N / 8);
        mgemm_kernel<8, 8, 2, 2><<<g, 256, 0, stream>>>(A2n, B2n, hn2, N_NODES, 128, 8, a1_o,
                                                        128, d2, a2_o, 0, g2v);
    }
    // 8) layer-2 edge attention -> eo2 (pre-elu), f2
    attn128_kernel<MAX_ARITY, true><<<(N_EDGES + 3) / 4, 256, 0, stream>>>(
        edge_list, hn2, c2, d2, a2_o, eo2, f2, N_EDGES);
    // 9) layer-2 node attention -> no2 (pre-elu)
    attn128_kernel<MAX_DEG, false><<<(N_NODES + 3) / 4, 256, 0, stream>>>(
        node_list, eo2, g2v, f2, nullptr, no2, nullptr, N_NODES);
    // 10) batch gather
    batch_kernel<<<(BATCH * 7 + 3) / 4, 256, 0, stream>>>(batch_inputs, eo2, no2, out);
}

// Round 4
// 255.439 us; speedup vs baseline: 2.5292x; 1.2600x over previous
//
#include <hip/hip_runtime.h>
#include <math.h>

#define N_NODES 50000
#define N_EDGES 25000
#define MAX_ARITY 6
#define MAX_DEG 8
#define NFEAT 128
#define NHID 64
#define NEMB 128
#define NHEADS 4
#define BATCH 4096

// padded m-tile counts (16 rows per tile, 8 tiles per GEMM block)
#define MT_N 3128   // ceil(50000/128)*8 -> rows padded to 50048

typedef __bf16 bf16x8 __attribute__((ext_vector_type(8)));
typedef __bf16 bf16x4 __attribute__((ext_vector_type(4)));
typedef float f32x4 __attribute__((ext_vector_type(4)));

__device__ __forceinline__ float wave_sum(float v) {
#pragma unroll
    for (int off = 1; off < 64; off <<= 1) v += __shfl_xor(v, off);
    return v;
}
__device__ __forceinline__ float group32_sum(float v) {
#pragma unroll
    for (int off = 1; off < 32; off <<= 1) v += __shfl_xor(v, off);
    return v;
}
__device__ __forceinline__ float group16_sum(float v) {
#pragma unroll
    for (int off = 1; off < 16; off <<= 1) v += __shfl_xor(v, off);
    return v;
}
__device__ __forceinline__ float group8_sum(float v) {
#pragma unroll
    for (int off = 1; off < 8; off <<= 1) v += __shfl_xor(v, off);
    return v;
}
__device__ __forceinline__ float lrelu(float x) { return x >= 0.f ? x : 0.2f * x; }
__device__ __forceinline__ float eluf(float x) { return x > 0.f ? x : expm1f(x); }

// ---------------------------------------------------------------------------
// repack: f32 row-major (M x K) -> bf16 MFMA A-fragment order
// dst[mt][kt][lane][8]: row = mt*16+(lane&15), k = kt*32+(lane>>4)*8+j
// ---------------------------------------------------------------------------
__global__ __launch_bounds__(256) void repack_kernel(const float* __restrict__ src,
                                                     __bf16* __restrict__ dst, int M, int K,
                                                     int KT, int total) {
    int t = blockIdx.x * 256 + threadIdx.x;
    if (t >= total) return;
    int lane = t & 63;
    int kt = (t >> 6) % KT;
    int mt = t / (64 * KT);
    int row = mt * 16 + (lane & 15);
    int ks = kt * 32 + (lane >> 4) * 8;
    float v[8];
    if (row < M) {
        float4 p0 = *reinterpret_cast<const float4*>(src + (size_t)row * K + ks);
        float4 p1 = *reinterpret_cast<const float4*>(src + (size_t)row * K + ks + 4);
        v[0] = p0.x; v[1] = p0.y; v[2] = p0.z; v[3] = p0.w;
        v[4] = p1.x; v[5] = p1.y; v[6] = p1.z; v[7] = p1.w;
    } else {
#pragma unroll
        for (int j = 0; j < 8; ++j) v[j] = 0.f;
    }
    bf16x8 o;
#pragma unroll
    for (int j = 0; j < 8; ++j) o[j] = (__bf16)v[j];
    reinterpret_cast<bf16x8*>(dst)[t] = o;
}

// ---------------------------------------------------------------------------
// bconv: weights f32 -> bf16 B-fragment order
// ---------------------------------------------------------------------------
template <bool HEADED>
__global__ __launch_bounds__(256) void bconv_kernel(const float* __restrict__ src,
                                                    __bf16* __restrict__ dst, int KT, int NT,
                                                    int N) {
    int t = blockIdx.x * 256 + threadIdx.x;
    if (t >= KT * NT * 64) return;
    int lane = t & 63;
    int nt = (t >> 6) % NT;
    int kt = t / (64 * NT);
    int k0 = kt * 32 + (lane >> 4) * 8;
    bf16x8 o;
#pragma unroll
    for (int j = 0; j < 8; ++j) {
        int k = k0 + j;
        float v;
        if (HEADED) {
            int h = nt >> 2;
            int nl = (nt & 3) * 16 + (lane & 15);
            v = src[(h * NFEAT + k) * NHID + nl];
        } else {
            int n = nt * 16 + (lane & 15);
            v = src[(size_t)k * N + n];
        }
        o[j] = (__bf16)v;
    }
    reinterpret_cast<bf16x8*>(dst)[t] = o;
}

// ---------------------------------------------------------------------------
// he-elimination vectors
// ---------------------------------------------------------------------------
__global__ void wvec1_kernel(const float* __restrict__ We, const float* __restrict__ a1,
                             float* __restrict__ wc1) {
    int t = blockIdx.x * 256 + threadIdx.x;
    if (t >= 512) return;
    int h = t >> 7, k = t & 127;
    float s = 0.f;
    for (int j = 0; j < 64; ++j) s += We[(h * NFEAT + k) * NHID + j] * a1[h * 128 + j];
    wc1[t] = s;
}
__global__ void wvec2_kernel(const float* __restrict__ Weo, const float* __restrict__ a1o,
                             float* __restrict__ wc2) {
    int t = blockIdx.x * 256 + threadIdx.x;
    if (t >= 256) return;
    float s = 0.f;
    for (int j = 0; j < 128; ++j) s += Weo[(size_t)t * 128 + j] * a1o[j];
    wc2[t] = s;
}

// c1[m][h] = sum_k edge_embs[m][k] * wc1[h][k]
__global__ __launch_bounds__(256) void c1_kernel(const float* __restrict__ X,
                                                 const float* __restrict__ wc1,
                                                 float* __restrict__ c1, int rows) {
    int r = blockIdx.x * 4 + (threadIdx.x >> 6);
    int lane = threadIdx.x & 63;
    if (r >= rows) return;
    float x0 = X[(size_t)r * 128 + lane];
    float x1 = X[(size_t)r * 128 + 64 + lane];
#pragma unroll
    for (int h = 0; h < 4; ++h) {
        float s = wave_sum(x0 * wc1[h * 128 + lane] + x1 * wc1[h * 128 + 64 + lane]);
        if (lane == 0) c1[r * 4 + h] = s;
    }
}

// ---------------------------------------------------------------------------
// LDS-free MFMA GEMM; C written as bf16 (tables are gather-only downstream).
// ---------------------------------------------------------------------------
template <int KT, int BNF, int DOTMODE, int NDOTV>
__global__ __launch_bounds__(256) void mgemm_kernel(
    const __bf16* __restrict__ A, const __bf16* __restrict__ B, __bf16* __restrict__ C, int M,
    int N, int NTB, const float* __restrict__ vA, int offA, float* __restrict__ outA,
    const float* __restrict__ vB, int offB, float* __restrict__ outB) {
    const int w = threadIdx.x >> 6, l = threadIdx.x & 63;
    const int mtb = blockIdx.y * 8 + w * 2;
    const int nbf = blockIdx.x * BNF;
    f32x4 acc[2][BNF];
#pragma unroll
    for (int i = 0; i < 2; ++i)
#pragma unroll
        for (int j = 0; j < BNF; ++j) acc[i][j] = (f32x4){0.f, 0.f, 0.f, 0.f};
    const bf16x8* A0 = reinterpret_cast<const bf16x8*>(A) + (size_t)mtb * KT * 64 + l;
    const bf16x8* A1 = A0 + KT * 64;
    const bf16x8* Bp = reinterpret_cast<const bf16x8*>(B) + l;
#pragma unroll
    for (int kt = 0; kt < KT; ++kt) {
        bf16x8 a0 = A0[kt * 64];
        bf16x8 a1 = A1[kt * 64];
#pragma unroll
        for (int nj = 0; nj < BNF; ++nj) {
            bf16x8 b = Bp[((size_t)kt * NTB + nbf + nj) * 64];
            acc[0][nj] = __builtin_amdgcn_mfma_f32_16x16x32_bf16(a0, b, acc[0][nj], 0, 0, 0);
            acc[1][nj] = __builtin_amdgcn_mfma_f32_16x16x32_bf16(a1, b, acc[1][nj], 0, 0, 0);
        }
    }
    const int rq = (l >> 4) * 4;
    const int cl = l & 15;
#pragma unroll
    for (int mi = 0; mi < 2; ++mi) {
        int mbase = (mtb + mi) * 16 + rq;
#pragma unroll
        for (int q = 0; q < 4; ++q) {
            int m = mbase + q;
            if (m < M) {
#pragma unroll
                for (int nj = 0; nj < BNF; ++nj)
                    C[(size_t)m * N + (nbf + nj) * 16 + cl] = (__bf16)acc[mi][nj][q];
            }
        }
    }
    if (DOTMODE) {
        float va[BNF], vb[BNF];
        const int vbase = (DOTMODE == 1) ? (nbf >> 2) * 128 : 0;
#pragma unroll
        for (int nj = 0; nj < BNF; ++nj) {
            int col = (DOTMODE == 1) ? ((nbf + nj) & 3) * 16 + cl : (nbf + nj) * 16 + cl;
            va[nj] = vA[vbase + offA + col];
            if (NDOTV >= 2) vb[nj] = vB[vbase + offB + col];
        }
        const int outStride = (DOTMODE == 1) ? 4 : 1;
        const int outOff = (DOTMODE == 1) ? (nbf >> 2) : 0;
#pragma unroll
        for (int mi = 0; mi < 2; ++mi) {
#pragma unroll
            for (int q = 0; q < 4; ++q) {
                float pA = 0.f, pB = 0.f;
#pragma unroll
                for (int nj = 0; nj < BNF; ++nj) {
                    pA += acc[mi][nj][q] * va[nj];
                    if (NDOTV >= 2) pB += acc[mi][nj][q] * vb[nj];
                }
                pA = group16_sum(pA);
                if (NDOTV >= 2) pB = group16_sum(pB);
                int m = (mtb + mi) * 16 + rq + q;
                if (cl == 0 && m < M) {
                    outA[(size_t)m * outStride + outOff] = pA;
                    if (NDOTV >= 2) outB[(size_t)m * outStride + outOff] = pB;
                }
            }
        }
    }
}

// ---------------------------------------------------------------------------
// Layer-1 EDGE attention: 2 edges per wave; 32 lanes/edge, lane owns 8 feats
// (bf16x8 gather, head h = lp>>3). Outputs: eo1 bf16, f1 (per-head dot,
// pre-elu), c2 (full-row dot of elu vs wc2).
// ---------------------------------------------------------------------------
__global__ __launch_bounds__(256) void attn64e_kernel(
    const int* __restrict__ nbr, const __bf16* __restrict__ feat,
    const float* __restrict__ sdot, const float* __restrict__ ndot,
    const float* __restrict__ a2v, const float* __restrict__ wc2, __bf16* __restrict__ eo1,
    float* __restrict__ f1, float* __restrict__ c2, int rows) {
    const int lane = threadIdx.x & 63;
    const int half = lane >> 5, lp = lane & 31;
    const int r = (blockIdx.x * 4 + (threadIdx.x >> 6)) * 2 + half;
    if (r >= rows) return;
    const int h = lp >> 3;
    const float c = sdot[r * 4 + h];
    int id[MAX_ARITY];
    float wgt[MAX_ARITY];
    float smax = -1e30f;
#pragma unroll
    for (int a = 0; a < MAX_ARITY; ++a) {
        int v = nbr[r * MAX_ARITY + a];
        id[a] = (v > 0) ? (v - 1) : 0;
        if (v > 0) {
            float s = lrelu(c + ndot[(size_t)id[a] * 4 + h]);
            wgt[a] = s;
            smax = fmaxf(smax, s);
        } else {
            wgt[a] = -3e30f;
        }
    }
    float denom = 0.f;
#pragma unroll
    for (int a = 0; a < MAX_ARITY; ++a) {
        float ex = (wgt[a] > -1e30f) ? expf(wgt[a] - smax) : 0.f;
        wgt[a] = ex;
        denom += ex;
    }
    float inv = 1.f / denom;
    float acc[8] = {0.f, 0.f, 0.f, 0.f, 0.f, 0.f, 0.f, 0.f};
#pragma unroll
    for (int a = 0; a < MAX_ARITY; ++a) {
        if (wgt[a] > 0.f) {
            bf16x8 f8 = *reinterpret_cast<const bf16x8*>(feat + (size_t)id[a] * 256 + lp * 8);
#pragma unroll
            for (int j = 0; j < 8; ++j) acc[j] = fmaf(wgt[a], (float)f8[j], acc[j]);
        }
    }
    bf16x8 o;
#pragma unroll
    for (int j = 0; j < 8; ++j) {
        acc[j] *= inv;
        o[j] = (__bf16)acc[j];
    }
    *reinterpret_cast<bf16x8*>(eo1 + (size_t)r * 256 + lp * 8) = o;
    // f1: per-head dot with a2[h, 64:128] on pre-elu values
    float p = 0.f;
#pragma unroll
    for (int j = 0; j < 8; ++j) p += acc[j] * a2v[h * 128 + 64 + (lp & 7) * 8 + j];
    p = group8_sum(p);
    if ((lp & 7) == 0) f1[r * 4 + h] = p;
    // c2: full-row dot of elu(eo1) with wc2
    float p2 = 0.f;
#pragma unroll
    for (int j = 0; j < 8; ++j) p2 += eluf(acc[j]) * wc2[lp * 8 + j];
    p2 = group32_sum(p2);
    if (lp == 0) c2[r] = p2;
}

// ---------------------------------------------------------------------------
// Layer-1 NODE attention: 2 nodes/wave; 32 lanes/node own 8 feats each;
// writes elu(out) directly as bf16 A-fragments for GEMM2 (KT=8).
// lane lp owns f = 8*lp..8*lp+7 -> kt = lp>>2, g = lp&3, j = 0..7 contiguous.
// ---------------------------------------------------------------------------
__global__ __launch_bounds__(256) void attn64n_kernel(const int* __restrict__ nbr,
                                                      const __bf16* __restrict__ feat,
                                                      const float* __restrict__ sdot,
                                                      const float* __restrict__ ndot,
                                                      __bf16* __restrict__ Afrag, int rows,
                                                      int rowsPad) {
    const int lane = threadIdx.x & 63;
    const int half = lane >> 5, lp = lane & 31;
    const int r = (blockIdx.x * 4 + (threadIdx.x >> 6)) * 2 + half;
    if (r >= rowsPad) return;
    const int rr = r & 15, mt = r >> 4;
    const int kt = lp >> 2, g = lp & 3;
    __bf16* dptr = Afrag + ((((size_t)mt * 8 + kt) * 64 + g * 16 + rr) << 3);
    if (r >= rows) {
        bf16x8 z;
#pragma unroll
        for (int j = 0; j < 8; ++j) z[j] = (__bf16)0.f;
        *reinterpret_cast<bf16x8*>(dptr) = z;
        return;
    }
    const int h = lp >> 3;
    const float c = sdot[r * 4 + h];
    int id[MAX_DEG];
    float wgt[MAX_DEG];
    float smax = -1e30f;
#pragma unroll
    for (int a = 0; a < MAX_DEG; ++a) {
        int v = nbr[r * MAX_DEG + a];
        id[a] = (v > 0) ? (v - 1) : 0;
        if (v > 0) {
            float s = lrelu(c + ndot[(size_t)id[a] * 4 + h]);
            wgt[a] = s;
            smax = fmaxf(smax, s);
        } else {
            wgt[a] = -3e30f;
        }
    }
    float denom = 0.f;
#pragma unroll
    for (int a = 0; a < MAX_DEG; ++a) {
        float ex = (wgt[a] > -1e30f) ? expf(wgt[a] - smax) : 0.f;
        wgt[a] = ex;
        denom += ex;
    }
    float inv = 1.f / denom;
    float acc[8] = {0.f, 0.f, 0.f, 0.f, 0.f, 0.f, 0.f, 0.f};
#pragma unroll
    for (int a = 0; a < MAX_DEG; ++a) {
        if (wgt[a] > 0.f) {
            bf16x8 f8 = *reinterpret_cast<const bf16x8*>(feat + (size_t)id[a] * 256 + lp * 8);
#pragma unroll
            for (int j = 0; j < 8; ++j) acc[j] = fmaf(wgt[a], (float)f8[j], acc[j]);
        }
    }
    bf16x8 o;
#pragma unroll
    for (int j = 0; j < 8; ++j) o[j] = (__bf16)eluf(acc[j] * inv);
    *reinterpret_cast<bf16x8*>(dptr) = o;
}

// ---------------------------------------------------------------------------
// Layer-2 attention: 4 rows/wave; 16 lanes/row own 8 feats each (bf16x8).
// ---------------------------------------------------------------------------
template <int NNBR, bool DOT>
__global__ __launch_bounds__(256) void attn128_kernel(const int* __restrict__ nbr,
                                                      const __bf16* __restrict__ feat,
                                                      const float* __restrict__ sdot,
                                                      const float* __restrict__ ndot,
                                                      const float* __restrict__ fvec,
                                                      __bf16* __restrict__ outF,
                                                      float* __restrict__ outDot, int rows) {
    const int lane = threadIdx.x & 63;
    const int qt = lane >> 4, lq = lane & 15;
    const int r = (blockIdx.x * 4 + (threadIdx.x >> 6)) * 4 + qt;
    if (r >= rows) return;
    const float c = sdot[r];
    int id[NNBR];
    float wgt[NNBR];
    float smax = -1e30f;
#pragma unroll
    for (int a = 0; a < NNBR; ++a) {
        int v = nbr[r * NNBR + a];
        id[a] = (v > 0) ? (v - 1) : 0;
        if (v > 0) {
            float s = lrelu(c + ndot[v - 1]);
            wgt[a] = s;
            smax = fmaxf(smax, s);
        } else {
            wgt[a] = -3e30f;
        }
    }
    float denom = 0.f;
#pragma unroll
    for (int a = 0; a < NNBR; ++a) {
        float ex = (wgt[a] > -1e30f) ? expf(wgt[a] - smax) : 0.f;
        wgt[a] = ex;
        denom += ex;
    }
    float inv = 1.f / denom;
    float acc[8] = {0.f, 0.f, 0.f, 0.f, 0.f, 0.f, 0.f, 0.f};
#pragma unroll
    for (int a = 0; a < NNBR; ++a) {
        if (wgt[a] > 0.f) {
            bf16x8 f8 = *reinterpret_cast<const bf16x8*>(feat + (size_t)id[a] * 128 + lq * 8);
#pragma unroll
            for (int j = 0; j < 8; ++j) acc[j] = fmaf(wgt[a], (float)f8[j], acc[j]);
        }
    }
    bf16x8 o;
#pragma unroll
    for (int j = 0; j < 8; ++j) {
        acc[j] *= inv;
        o[j] = (__bf16)acc[j];
    }
    *reinterpret_cast<bf16x8*>(outF + (size_t)r * 128 + lq * 8) = o;
    if (DOT) {
        float p = 0.f;
#pragma unroll
        for (int j = 0; j < 8; ++j) p += acc[j] * fvec[128 + lq * 8 + j];
        p = group16_sum(p);
        if (lq == 0) outDot[r] = p;
    }
}

// ---------------------------------------------------------------------------
// Batch gather: 2 (b,slot) pairs per wave; 32 lanes own 4 feats each.
// ---------------------------------------------------------------------------
__global__ __launch_bounds__(256) void batch_kernel(const int* __restrict__ bi,
                                                    const __bf16* __restrict__ eo2,
                                                    const __bf16* __restrict__ no2,
                                                    float* __restrict__ out) {
    const int lane = threadIdx.x & 63;
    const int half = lane >> 5, lp = lane & 31;
    const int gw = (blockIdx.x * 4 + (threadIdx.x >> 6)) * 2 + half;
    if (gw >= BATCH * 7) return;
    int b = gw / 7, s = gw % 7;
    int last_nz = -1;
#pragma unroll
    for (int j = 0; j < 7; ++j)
        if (bi[b * 7 + j] != 0) last_nz = j;
    float4 v;
    if (s == 0) {
        int e = bi[b * 7] - 1;
        bf16x4 t = *reinterpret_cast<const bf16x4*>(eo2 + (size_t)e * 128 + lp * 4);
        v = make_float4(eluf((float)t[0]), eluf((float)t[1]), eluf((float)t[2]),
                        eluf((float)t[3]));
    } else if (s <= last_nz) {
        int nid = bi[b * 7 + s] - 1;
        if (nid < 0) nid += N_NODES;
        bf16x4 t = *reinterpret_cast<const bf16x4*>(no2 + (size_t)nid * 128 + lp * 4);
        v = make_float4(eluf((float)t[0]), eluf((float)t[1]), eluf((float)t[2]),
                        eluf((float)t[3]));
    } else {
        v = make_float4(1.f, 1.f, 1.f, 1.f);
    }
    *reinterpret_cast<float4*>(out + (size_t)b * 896 + s * 128 + lp * 4) = v;
}

// ---------------------------------------------------------------------------
extern "C" void kernel_launch(void* const* d_in, const int* in_sizes, int n_in,
                              void* d_out, int out_size, void* d_ws, size_t ws_size,
                              hipStream_t stream) {
    const int* batch_inputs = (const int*)d_in[0];
    const int* edge_list = (const int*)d_in[1];
    const int* node_list = (const int*)d_in[2];
    const float* node_embs = (const float*)d_in[3];
    const float* edge_embs = (const float*)d_in[4];
    const float* Wn = (const float*)d_in[5];
    const float* We = (const float*)d_in[6];
    const float* a1 = (const float*)d_in[7];
    const float* a2 = (const float*)d_in[8];
    const float* Wn_o = (const float*)d_in[9];
    const float* We_o = (const float*)d_in[10];
    const float* a1_o = (const float*)d_in[11];
    const float* a2_o = (const float*)d_in[12];
    float* out = (float*)d_out;
    char* ws = (char*)d_ws;

    // ---- workspace layout (bytes) ----
    __bf16* A1n = (__bf16*)(ws);                 // 12,812,288
    __bf16* B1n = (__bf16*)(ws + 12812288);      // 65,536
    __bf16* B2n = (__bf16*)(ws + 12877824);      // 65,536
    float* wc1 = (float*)(ws + 12943360);        // 2,048
    float* wc2 = (float*)(ws + 12945408);        // 1,024
    float* c1 = (float*)(ws + 12946432);         // 400,000
    float* d1 = (float*)(ws + 13346432);         // 800,000
    float* g1v = (float*)(ws + 14146432);        // 800,000
    float* f1 = (float*)(ws + 14946432);         // 400,000
    float* c2 = (float*)(ws + 15346432);         // 100,000
    float* d2 = (float*)(ws + 15446432);         // 200,000
    float* g2v = (float*)(ws + 15646432);        // 200,000
    float* f2 = (float*)(ws + 15846432);         // 100,000
    __bf16* hn1 = (__bf16*)(ws + 16000000);      // 25,600,000 (50000x256 bf16)
    __bf16* A2n = (__bf16*)(ws + 41600000);      // 25,624,576
    __bf16* hn2 = (__bf16*)(ws + 67224576);      // 12,800,000 (50000x128 bf16)
    __bf16* eo1 = (__bf16*)(ws + 80024576);      // 12,800,000 (dead after attn64n)
    __bf16* no2 = (__bf16*)(ws + 80024576);      // overlays dead eo1
    __bf16* eo2 = (__bf16*)(ws + 92824576);      // 6,400,000 -> ends 99,224,576
    // total ~99.2 MB

    // 1) repack node_embs -> A1n (bf16 frag order, padded)
    {
        int total = MT_N * 4 * 64;
        repack_kernel<<<(total + 255) / 256, 256, 0, stream>>>(node_embs, A1n, N_NODES, 128, 4,
                                                               total);
    }
    // 2) weight conversions
    bconv_kernel<true><<<16, 256, 0, stream>>>(Wn, B1n, 4, 16, 64);
    bconv_kernel<false><<<16, 256, 0, stream>>>(Wn_o, B2n, 8, 8, 128);
    // 3) he-elimination vectors + c1 matvec
    wvec1_kernel<<<2, 256, 0, stream>>>(We, a1, wc1);
    wvec2_kernel<<<1, 256, 0, stream>>>(We_o, a1_o, wc2);
    c1_kernel<<<(N_EDGES + 3) / 4, 256, 0, stream>>>(edge_embs, wc1, c1, N_EDGES);

    // 4) G1n: hn1(bf16) = node_embs @ Wn  (+ d1, g1v from f32 acc)
    {
        dim3 g(4, MT_N / 8);
        mgemm_kernel<4, 4, 1, 2><<<g, 256, 0, stream>>>(A1n, B1n, hn1, N_NODES, 256, 16, a1, 64,
                                                        d1, a2, 0, g1v);
    }
    // 5) layer-1 edge attention -> eo1(bf16), f1, c2   [2 edges/wave]
    attn64e_kernel<<<(N_EDGES / 2 + 3) / 4, 256, 0, stream>>>(edge_list, hn1, c1, d1, a2, wc2,
                                                              eo1, f1, c2, N_EDGES);
    // 6) layer-1 node attention -> A2n (elu'd bf16 frags)   [2 nodes/wave]
    attn64n_kernel<<<(MT_N * 16 / 2 + 3) / 4, 256, 0, stream>>>(node_list, eo1, g1v, f1, A2n,
                                                                N_NODES, MT_N * 16);
    // 7) G2n: hn2(bf16) = no1 @ Wn_o (+ d2, g2v)
    {
        dim3 g(1, MT_N / 8);
        mgemm_kernel<8, 8, 2, 2><<<g, 256, 0, stream>>>(A2n, B2n, hn2, N_NODES, 128, 8, a1_o,
                                                        128, d2, a2_o, 0, g2v);
    }
    // 8) layer-2 edge attention -> eo2(bf16), f2   [4 rows/wave]
    attn128_kernel<MAX_ARITY, true><<<(N_EDGES / 4 + 3) / 4, 256, 0, stream>>>(
        edge_list, hn2, c2, d2, a2_o, eo2, f2, N_EDGES);
    // 9) layer-2 node attention -> no2(bf16)   [4 rows/wave]
    attn128_kernel<MAX_DEG, false><<<(N_NODES / 4 + 3) / 4, 256, 0, stream>>>(
        node_list, eo2, g2v, f2, nullptr, no2, nullptr, N_NODES);
    // 10) batch gather   [2 pairs/wave]
    batch_kernel<<<(BATCH * 7 / 2 + 3) / 4, 256, 0, stream>>>(batch_inputs, eo2, no2, out);
}

// Round 5
// 210.760 us; speedup vs baseline: 3.0654x; 1.2120x over previous
//
#include <hip/hip_runtime.h>
#include <math.h>

#define N_NODES 50000
#define N_EDGES 25000
#define MAX_ARITY 6
#define MAX_DEG 8
#define NFEAT 128
#define NHID 64
#define NEMB 128
#define NHEADS 4
#define BATCH 4096

// padded m-tile counts (16 rows per tile)
#define MT_N 3128   // ceil(50000/128)*8 -> rows padded to 50048

typedef __bf16 bf16x8 __attribute__((ext_vector_type(8)));
typedef __bf16 bf16x4 __attribute__((ext_vector_type(4)));
typedef float f32x4 __attribute__((ext_vector_type(4)));

__device__ __forceinline__ float wave_sum(float v) {
#pragma unroll
    for (int off = 1; off < 64; off <<= 1) v += __shfl_xor(v, off);
    return v;
}
__device__ __forceinline__ float group32_sum(float v) {
#pragma unroll
    for (int off = 1; off < 32; off <<= 1) v += __shfl_xor(v, off);
    return v;
}
__device__ __forceinline__ float group16_sum(float v) {
#pragma unroll
    for (int off = 1; off < 16; off <<= 1) v += __shfl_xor(v, off);
    return v;
}
__device__ __forceinline__ float group8_sum(float v) {
#pragma unroll
    for (int off = 1; off < 8; off <<= 1) v += __shfl_xor(v, off);
    return v;
}
__device__ __forceinline__ float lrelu(float x) { return x >= 0.f ? x : 0.2f * x; }
__device__ __forceinline__ float eluf(float x) { return x > 0.f ? x : expm1f(x); }

// ---------------------------------------------------------------------------
// PREP mega-kernel: repack(A1n) + bconv(B1n) + bconv(B2n) + wvec1 + wvec2 + c1
// branched on blockIdx.x range (all sub-tasks independent; merged so they
// co-schedule in one dispatch instead of serializing on the stream).
// ---------------------------------------------------------------------------
#define PREP_REPACK_BLKS 3128   // MT_N*4*64/256
#define PREP_BCONV1_BLKS 16
#define PREP_BCONV2_BLKS 16
#define PREP_WVEC1_BLKS 2
#define PREP_WVEC2_BLKS 1
#define PREP_C1_BLKS 6250       // N_EDGES/4
#define PREP_TOTAL_BLKS (PREP_REPACK_BLKS + PREP_BCONV1_BLKS + PREP_BCONV2_BLKS + \
                         PREP_WVEC1_BLKS + PREP_WVEC2_BLKS + PREP_C1_BLKS)

__global__ __launch_bounds__(256) void prep_kernel(
    const float* __restrict__ node_embs, const float* __restrict__ edge_embs,
    const float* __restrict__ Wn, const float* __restrict__ We, const float* __restrict__ a1,
    const float* __restrict__ Wn_o, const float* __restrict__ We_o,
    const float* __restrict__ a1_o, __bf16* __restrict__ A1n, __bf16* __restrict__ B1n,
    __bf16* __restrict__ B2n, float* __restrict__ wc1, float* __restrict__ wc2,
    float* __restrict__ c1) {
    int blk = blockIdx.x;
    if (blk < PREP_REPACK_BLKS) {
        // repack node_embs (f32, row-major 50000x128) -> bf16 A-frag order, KT=4
        int t = blk * 256 + threadIdx.x;
        int lane = t & 63;
        int kt = (t >> 6) & 3;
        int mt = t >> 8;
        int row = mt * 16 + (lane & 15);
        int ks = kt * 32 + (lane >> 4) * 8;
        float v[8];
        if (row < N_NODES) {
            float4 p0 = *reinterpret_cast<const float4*>(node_embs + (size_t)row * 128 + ks);
            float4 p1 = *reinterpret_cast<const float4*>(node_embs + (size_t)row * 128 + ks + 4);
            v[0] = p0.x; v[1] = p0.y; v[2] = p0.z; v[3] = p0.w;
            v[4] = p1.x; v[5] = p1.y; v[6] = p1.z; v[7] = p1.w;
        } else {
#pragma unroll
            for (int j = 0; j < 8; ++j) v[j] = 0.f;
        }
        bf16x8 o;
#pragma unroll
        for (int j = 0; j < 8; ++j) o[j] = (__bf16)v[j];
        reinterpret_cast<bf16x8*>(A1n)[t] = o;
        return;
    }
    blk -= PREP_REPACK_BLKS;
    if (blk < PREP_BCONV1_BLKS) {
        // Wn (4,128,64) -> B1n frag order [kt][nt][lane][8], KT=4, NT=16
        int t = blk * 256 + threadIdx.x;
        int lane = t & 63;
        int nt = (t >> 6) & 15;
        int kt = t >> 10;
        int k0 = kt * 32 + (lane >> 4) * 8;
        int h = nt >> 2;
        int nl = (nt & 3) * 16 + (lane & 15);
        bf16x8 o;
#pragma unroll
        for (int j = 0; j < 8; ++j) o[j] = (__bf16)Wn[(h * NFEAT + k0 + j) * NHID + nl];
        reinterpret_cast<bf16x8*>(B1n)[t] = o;
        return;
    }
    blk -= PREP_BCONV1_BLKS;
    if (blk < PREP_BCONV2_BLKS) {
        // Wn_o (256,128) -> B2n frag order, KT=8, NT=8
        int t = blk * 256 + threadIdx.x;
        int lane = t & 63;
        int nt = (t >> 6) & 7;
        int kt = t >> 9;
        int k0 = kt * 32 + (lane >> 4) * 8;
        int n = nt * 16 + (lane & 15);
        bf16x8 o;
#pragma unroll
        for (int j = 0; j < 8; ++j) o[j] = (__bf16)Wn_o[(size_t)(k0 + j) * 128 + n];
        reinterpret_cast<bf16x8*>(B2n)[t] = o;
        return;
    }
    blk -= PREP_BCONV2_BLKS;
    if (blk < PREP_WVEC1_BLKS) {
        int t = blk * 256 + threadIdx.x;
        int h = t >> 7, k = t & 127;
        float s = 0.f;
        for (int j = 0; j < 64; ++j) s += We[(h * NFEAT + k) * NHID + j] * a1[h * 128 + j];
        wc1[t] = s;
        return;
    }
    blk -= PREP_WVEC1_BLKS;
    if (blk < PREP_WVEC2_BLKS) {
        int t = threadIdx.x;
        float s = 0.f;
        for (int j = 0; j < 128; ++j) s += We_o[(size_t)t * 128 + j] * a1_o[j];
        wc2[t] = s;
        return;
    }
    blk -= PREP_WVEC2_BLKS;
    {
        // c1[m][h] = edge_embs[m] . wc1[h]
        int r = blk * 4 + (threadIdx.x >> 6);
        int lane = threadIdx.x & 63;
        if (r >= N_EDGES) return;
        float x0 = edge_embs[(size_t)r * 128 + lane];
        float x1 = edge_embs[(size_t)r * 128 + 64 + lane];
#pragma unroll
        for (int h = 0; h < 4; ++h) {
            float s = wave_sum(x0 * wc1[h * 128 + lane] + x1 * wc1[h * 128 + 64 + lane]);
            if (lane == 0) c1[r * 4 + h] = s;
        }
    }
}

// ---------------------------------------------------------------------------
// LDS-free MFMA GEMM; C written as bf16. MPW = m-tiles per wave (1 or 2).
// ---------------------------------------------------------------------------
template <int KT, int BNF, int DOTMODE, int NDOTV, int MPW>
__global__ __launch_bounds__(256) void mgemm_kernel(
    const __bf16* __restrict__ A, const __bf16* __restrict__ B, __bf16* __restrict__ C, int M,
    int N, int NTB, const float* __restrict__ vA, int offA, float* __restrict__ outA,
    const float* __restrict__ vB, int offB, float* __restrict__ outB) {
    const int w = threadIdx.x >> 6, l = threadIdx.x & 63;
    const int mtb = blockIdx.y * (4 * MPW) + w * MPW;
    const int nbf = blockIdx.x * BNF;
    f32x4 acc[MPW][BNF];
#pragma unroll
    for (int i = 0; i < MPW; ++i)
#pragma unroll
        for (int j = 0; j < BNF; ++j) acc[i][j] = (f32x4){0.f, 0.f, 0.f, 0.f};
    const bf16x8* Ap = reinterpret_cast<const bf16x8*>(A) + (size_t)mtb * KT * 64 + l;
    const bf16x8* Bp = reinterpret_cast<const bf16x8*>(B) + l;
#pragma unroll
    for (int kt = 0; kt < KT; ++kt) {
        bf16x8 a[MPW];
#pragma unroll
        for (int mi = 0; mi < MPW; ++mi) a[mi] = Ap[((size_t)mi * KT + kt) * 64];
#pragma unroll
        for (int nj = 0; nj < BNF; ++nj) {
            bf16x8 b = Bp[((size_t)kt * NTB + nbf + nj) * 64];
#pragma unroll
            for (int mi = 0; mi < MPW; ++mi)
                acc[mi][nj] = __builtin_amdgcn_mfma_f32_16x16x32_bf16(a[mi], b, acc[mi][nj], 0, 0, 0);
        }
    }
    const int rq = (l >> 4) * 4;
    const int cl = l & 15;
#pragma unroll
    for (int mi = 0; mi < MPW; ++mi) {
        int mbase = (mtb + mi) * 16 + rq;
#pragma unroll
        for (int q = 0; q < 4; ++q) {
            int m = mbase + q;
            if (m < M) {
#pragma unroll
                for (int nj = 0; nj < BNF; ++nj)
                    C[(size_t)m * N + (nbf + nj) * 16 + cl] = (__bf16)acc[mi][nj][q];
            }
        }
    }
    if (DOTMODE) {
        float va[BNF], vb[BNF];
        const int vbase = (DOTMODE == 1) ? (nbf >> 2) * 128 : 0;
#pragma unroll
        for (int nj = 0; nj < BNF; ++nj) {
            int col = (DOTMODE == 1) ? ((nbf + nj) & 3) * 16 + cl : (nbf + nj) * 16 + cl;
            va[nj] = vA[vbase + offA + col];
            if (NDOTV >= 2) vb[nj] = vB[vbase + offB + col];
        }
        const int outStride = (DOTMODE == 1) ? 4 : 1;
        const int outOff = (DOTMODE == 1) ? (nbf >> 2) : 0;
#pragma unroll
        for (int mi = 0; mi < MPW; ++mi) {
#pragma unroll
            for (int q = 0; q < 4; ++q) {
                float pA = 0.f, pB = 0.f;
#pragma unroll
                for (int nj = 0; nj < BNF; ++nj) {
                    pA += acc[mi][nj][q] * va[nj];
                    if (NDOTV >= 2) pB += acc[mi][nj][q] * vb[nj];
                }
                pA = group16_sum(pA);
                if (NDOTV >= 2) pB = group16_sum(pB);
                int m = (mtb + mi) * 16 + rq + q;
                if (cl == 0 && m < M) {
                    outA[(size_t)m * outStride + outOff] = pA;
                    if (NDOTV >= 2) outB[(size_t)m * outStride + outOff] = pB;
                }
            }
        }
    }
}

// ---------------------------------------------------------------------------
// Layer-1 EDGE attention: 2 edges/wave, 32 lanes/edge, lane owns 8 feats.
// All neighbor feature rows prefetched into registers BEFORE score compute
// so L2-miss latency overlaps the softmax VALU work.
// ---------------------------------------------------------------------------
__global__ __launch_bounds__(256) void attn64e_kernel(
    const int* __restrict__ nbr, const __bf16* __restrict__ feat,
    const float* __restrict__ sdot, const float* __restrict__ ndot,
    const float* __restrict__ a2v, const float* __restrict__ wc2, __bf16* __restrict__ eo1,
    float* __restrict__ f1, float* __restrict__ c2, int rows) {
    const int lane = threadIdx.x & 63;
    const int half = lane >> 5, lp = lane & 31;
    const int r = (blockIdx.x * 4 + (threadIdx.x >> 6)) * 2 + half;
    if (r >= rows) return;
    const int h = lp >> 3;
    int id[MAX_ARITY];
    bool val[MAX_ARITY];
#pragma unroll
    for (int a = 0; a < MAX_ARITY; ++a) {
        int v = nbr[r * MAX_ARITY + a];
        val[a] = v > 0;
        id[a] = val[a] ? (v - 1) : 0;
    }
    // issue all gathers up-front
    bf16x8 f8[MAX_ARITY];
    float nd[MAX_ARITY];
#pragma unroll
    for (int a = 0; a < MAX_ARITY; ++a) {
        f8[a] = *reinterpret_cast<const bf16x8*>(feat + (size_t)id[a] * 256 + lp * 8);
        nd[a] = ndot[(size_t)id[a] * 4 + h];
    }
    const float c = sdot[r * 4 + h];
    float wgt[MAX_ARITY];
    float smax = -1e30f;
#pragma unroll
    for (int a = 0; a < MAX_ARITY; ++a) {
        float s = val[a] ? lrelu(c + nd[a]) : -3e30f;
        wgt[a] = s;
        if (val[a]) smax = fmaxf(smax, s);
    }
    float denom = 0.f;
#pragma unroll
    for (int a = 0; a < MAX_ARITY; ++a) {
        float ex = val[a] ? expf(wgt[a] - smax) : 0.f;
        wgt[a] = ex;
        denom += ex;
    }
    float inv = 1.f / denom;
    float acc[8] = {0.f, 0.f, 0.f, 0.f, 0.f, 0.f, 0.f, 0.f};
#pragma unroll
    for (int a = 0; a < MAX_ARITY; ++a)
#pragma unroll
        for (int j = 0; j < 8; ++j) acc[j] = fmaf(wgt[a], (float)f8[a][j], acc[j]);
    bf16x8 o;
#pragma unroll
    for (int j = 0; j < 8; ++j) {
        acc[j] *= inv;
        o[j] = (__bf16)acc[j];
    }
    *reinterpret_cast<bf16x8*>(eo1 + (size_t)r * 256 + lp * 8) = o;
    float p = 0.f;
#pragma unroll
    for (int j = 0; j < 8; ++j) p += acc[j] * a2v[h * 128 + 64 + (lp & 7) * 8 + j];
    p = group8_sum(p);
    if ((lp & 7) == 0) f1[r * 4 + h] = p;
    float p2 = 0.f;
#pragma unroll
    for (int j = 0; j < 8; ++j) p2 += eluf(acc[j]) * wc2[lp * 8 + j];
    p2 = group32_sum(p2);
    if (lp == 0) c2[r] = p2;
}

// ---------------------------------------------------------------------------
// Layer-1 NODE attention: 2 nodes/wave; prefetched gathers; writes elu(out)
// directly as bf16 A-fragments for GEMM2 (KT=8).
// ---------------------------------------------------------------------------
__global__ __launch_bounds__(256) void attn64n_kernel(const int* __restrict__ nbr,
                                                      const __bf16* __restrict__ feat,
                                                      const float* __restrict__ sdot,
                                                      const float* __restrict__ ndot,
                                                      __bf16* __restrict__ Afrag, int rows,
                                                      int rowsPad) {
    const int lane = threadIdx.x & 63;
    const int half = lane >> 5, lp = lane & 31;
    const int r = (blockIdx.x * 4 + (threadIdx.x >> 6)) * 2 + half;
    if (r >= rowsPad) return;
    const int rr = r & 15, mt = r >> 4;
    const int kt = lp >> 2, g = lp & 3;
    __bf16* dptr = Afrag + ((((size_t)mt * 8 + kt) * 64 + g * 16 + rr) << 3);
    if (r >= rows) {
        bf16x8 z;
#pragma unroll
        for (int j = 0; j < 8; ++j) z[j] = (__bf16)0.f;
        *reinterpret_cast<bf16x8*>(dptr) = z;
        return;
    }
    const int h = lp >> 3;
    int id[MAX_DEG];
    bool val[MAX_DEG];
#pragma unroll
    for (int a = 0; a < MAX_DEG; ++a) {
        int v = nbr[r * MAX_DEG + a];
        val[a] = v > 0;
        id[a] = val[a] ? (v - 1) : 0;
    }
    bf16x8 f8[MAX_DEG];
    float nd[MAX_DEG];
#pragma unroll
    for (int a = 0; a < MAX_DEG; ++a) {
        f8[a] = *reinterpret_cast<const bf16x8*>(feat + (size_t)id[a] * 256 + lp * 8);
        nd[a] = ndot[(size_t)id[a] * 4 + h];
    }
    const float c = sdot[r * 4 + h];
    float wgt[MAX_DEG];
    float smax = -1e30f;
#pragma unroll
    for (int a = 0; a < MAX_DEG; ++a) {
        float s = val[a] ? lrelu(c + nd[a]) : -3e30f;
        wgt[a] = s;
        if (val[a]) smax = fmaxf(smax, s);
    }
    float denom = 0.f;
#pragma unroll
    for (int a = 0; a < MAX_DEG; ++a) {
        float ex = val[a] ? expf(wgt[a] - smax) : 0.f;
        wgt[a] = ex;
        denom += ex;
    }
    float inv = 1.f / denom;
    float acc[8] = {0.f, 0.f, 0.f, 0.f, 0.f, 0.f, 0.f, 0.f};
#pragma unroll
    for (int a = 0; a < MAX_DEG; ++a)
#pragma unroll
        for (int j = 0; j < 8; ++j) acc[j] = fmaf(wgt[a], (float)f8[a][j], acc[j]);
    bf16x8 o;
#pragma unroll
    for (int j = 0; j < 8; ++j) o[j] = (__bf16)eluf(acc[j] * inv);
    *reinterpret_cast<bf16x8*>(dptr) = o;
}

// ---------------------------------------------------------------------------
// Layer-2 attention: 4 rows/wave; 16 lanes/row own 8 feats; prefetched.
// ---------------------------------------------------------------------------
template <int NNBR, bool DOT>
__global__ __launch_bounds__(256) void attn128_kernel(const int* __restrict__ nbr,
                                                      const __bf16* __restrict__ feat,
                                                      const float* __restrict__ sdot,
                                                      const float* __restrict__ ndot,
                                                      const float* __restrict__ fvec,
                                                      __bf16* __restrict__ outF,
                                                      float* __restrict__ outDot, int rows) {
    const int lane = threadIdx.x & 63;
    const int qt = lane >> 4, lq = lane & 15;
    const int r = (blockIdx.x * 4 + (threadIdx.x >> 6)) * 4 + qt;
    if (r >= rows) return;
    int id[NNBR];
    bool val[NNBR];
#pragma unroll
    for (int a = 0; a < NNBR; ++a) {
        int v = nbr[r * NNBR + a];
        val[a] = v > 0;
        id[a] = val[a] ? (v - 1) : 0;
    }
    bf16x8 f8[NNBR];
    float nd[NNBR];
#pragma unroll
    for (int a = 0; a < NNBR; ++a) {
        f8[a] = *reinterpret_cast<const bf16x8*>(feat + (size_t)id[a] * 128 + lq * 8);
        nd[a] = ndot[id[a]];
    }
    const float c = sdot[r];
    float wgt[NNBR];
    float smax = -1e30f;
#pragma unroll
    for (int a = 0; a < NNBR; ++a) {
        float s = val[a] ? lrelu(c + nd[a]) : -3e30f;
        wgt[a] = s;
        if (val[a]) smax = fmaxf(smax, s);
    }
    float denom = 0.f;
#pragma unroll
    for (int a = 0; a < NNBR; ++a) {
        float ex = val[a] ? expf(wgt[a] - smax) : 0.f;
        wgt[a] = ex;
        denom += ex;
    }
    float inv = 1.f / denom;
    float acc[8] = {0.f, 0.f, 0.f, 0.f, 0.f, 0.f, 0.f, 0.f};
#pragma unroll
    for (int a = 0; a < NNBR; ++a)
#pragma unroll
        for (int j = 0; j < 8; ++j) acc[j] = fmaf(wgt[a], (float)f8[a][j], acc[j]);
    bf16x8 o;
#pragma unroll
    for (int j = 0; j < 8; ++j) {
        acc[j] *= inv;
        o[j] = (__bf16)acc[j];
    }
    *reinterpret_cast<bf16x8*>(outF + (size_t)r * 128 + lq * 8) = o;
    if (DOT) {
        float p = 0.f;
#pragma unroll
        for (int j = 0; j < 8; ++j) p += acc[j] * fvec[128 + lq * 8 + j];
        p = group16_sum(p);
        if (lq == 0) outDot[r] = p;
    }
}

// ---------------------------------------------------------------------------
// Batch gather: 2 (b,slot) pairs per wave; 32 lanes own 4 feats each.
// ---------------------------------------------------------------------------
__global__ __launch_bounds__(256) void batch_kernel(const int* __restrict__ bi,
                                                    const __bf16* __restrict__ eo2,
                                                    const __bf16* __restrict__ no2,
                                                    float* __restrict__ out) {
    const int lane = threadIdx.x & 63;
    const int half = lane >> 5, lp = lane & 31;
    const int gw = (blockIdx.x * 4 + (threadIdx.x >> 6)) * 2 + half;
    if (gw >= BATCH * 7) return;
    int b = gw / 7, s = gw % 7;
    int last_nz = -1;
#pragma unroll
    for (int j = 0; j < 7; ++j)
        if (bi[b * 7 + j] != 0) last_nz = j;
    float4 v;
    if (s == 0) {
        int e = bi[b * 7] - 1;
        bf16x4 t = *reinterpret_cast<const bf16x4*>(eo2 + (size_t)e * 128 + lp * 4);
        v = make_float4(eluf((float)t[0]), eluf((float)t[1]), eluf((float)t[2]),
                        eluf((float)t[3]));
    } else if (s <= last_nz) {
        int nid = bi[b * 7 + s] - 1;
        if (nid < 0) nid += N_NODES;
        bf16x4 t = *reinterpret_cast<const bf16x4*>(no2 + (size_t)nid * 128 + lp * 4);
        v = make_float4(eluf((float)t[0]), eluf((float)t[1]), eluf((float)t[2]),
                        eluf((float)t[3]));
    } else {
        v = make_float4(1.f, 1.f, 1.f, 1.f);
    }
    *reinterpret_cast<float4*>(out + (size_t)b * 896 + s * 128 + lp * 4) = v;
}

// ---------------------------------------------------------------------------
extern "C" void kernel_launch(void* const* d_in, const int* in_sizes, int n_in,
                              void* d_out, int out_size, void* d_ws, size_t ws_size,
                              hipStream_t stream) {
    const int* batch_inputs = (const int*)d_in[0];
    const int* edge_list = (const int*)d_in[1];
    const int* node_list = (const int*)d_in[2];
    const float* node_embs = (const float*)d_in[3];
    const float* edge_embs = (const float*)d_in[4];
    const float* Wn = (const float*)d_in[5];
    const float* We = (const float*)d_in[6];
    const float* a1 = (const float*)d_in[7];
    const float* a2 = (const float*)d_in[8];
    const float* Wn_o = (const float*)d_in[9];
    const float* We_o = (const float*)d_in[10];
    const float* a1_o = (const float*)d_in[11];
    const float* a2_o = (const float*)d_in[12];
    float* out = (float*)d_out;
    char* ws = (char*)d_ws;

    // ---- workspace layout (bytes) ----
    __bf16* A1n = (__bf16*)(ws);                 // 12,812,288
    __bf16* B1n = (__bf16*)(ws + 12812288);      // 65,536
    __bf16* B2n = (__bf16*)(ws + 12877824);      // 65,536
    float* wc1 = (float*)(ws + 12943360);        // 2,048
    float* wc2 = (float*)(ws + 12945408);        // 1,024
    float* c1 = (float*)(ws + 12946432);         // 400,000
    float* d1 = (float*)(ws + 13346432);         // 800,000
    float* g1v = (float*)(ws + 14146432);        // 800,000
    float* f1 = (float*)(ws + 14946432);         // 400,000
    float* c2 = (float*)(ws + 15346432);         // 100,000
    float* d2 = (float*)(ws + 15446432);         // 200,000
    float* g2v = (float*)(ws + 15646432);        // 200,000
    float* f2 = (float*)(ws + 15846432);         // 100,000
    __bf16* hn1 = (__bf16*)(ws + 16000000);      // 25,600,000 (50000x256 bf16)
    __bf16* A2n = (__bf16*)(ws + 41600000);      // 25,624,576
    __bf16* hn2 = (__bf16*)(ws + 67224576);      // 12,800,000 (50000x128 bf16)
    __bf16* eo1 = (__bf16*)(ws + 80024576);      // 12,800,000 (dead after attn64n)
    __bf16* no2 = (__bf16*)(ws + 80024576);      // overlays dead eo1
    __bf16* eo2 = (__bf16*)(ws + 92824576);      // 6,400,000 -> ends 99,224,576

    // 1) merged prep: repack + bconv x2 + wvec x2 + c1
    prep_kernel<<<PREP_TOTAL_BLKS, 256, 0, stream>>>(node_embs, edge_embs, Wn, We, a1, Wn_o,
                                                     We_o, a1_o, A1n, B1n, B2n, wc1, wc2, c1);

    // 2) G1n: hn1(bf16) = node_embs @ Wn  (+ d1, g1v)   [MPW=2]
    {
        dim3 g(4, MT_N / 8);
        mgemm_kernel<4, 4, 1, 2, 2><<<g, 256, 0, stream>>>(A1n, B1n, hn1, N_NODES, 256, 16, a1,
                                                           64, d1, a2, 0, g1v);
    }
    // 3) layer-1 edge attention -> eo1(bf16), f1, c2
    attn64e_kernel<<<(N_EDGES / 2 + 3) / 4, 256, 0, stream>>>(edge_list, hn1, c1, d1, a2, wc2,
                                                              eo1, f1, c2, N_EDGES);
    // 4) layer-1 node attention -> A2n (elu'd bf16 frags)
    attn64n_kernel<<<(MT_N * 16 / 2 + 3) / 4, 256, 0, stream>>>(node_list, eo1, g1v, f1, A2n,
                                                                N_NODES, MT_N * 16);
    // 5) G2n: hn2(bf16) = no1 @ Wn_o (+ d2, g2v)   [MPW=1 -> 782 blocks]
    {
        dim3 g(1, MT_N / 4);
        mgemm_kernel<8, 8, 2, 2, 1><<<g, 256, 0, stream>>>(A2n, B2n, hn2, N_NODES, 128, 8, a1_o,
                                                           128, d2, a2_o, 0, g2v);
    }
    // 6) layer-2 edge attention -> eo2(bf16), f2
    attn128_kernel<MAX_ARITY, true><<<(N_EDGES / 4 + 3) / 4, 256, 0, stream>>>(
        edge_list, hn2, c2, d2, a2_o, eo2, f2, N_EDGES);
    // 7) layer-2 node attention -> no2(bf16)
    attn128_kernel<MAX_DEG, false><<<(N_NODES / 4 + 3) / 4, 256, 0, stream>>>(
        node_list, eo2, g2v, f2, nullptr, no2, nullptr, N_NODES);
    // 8) batch gather
    batch_kernel<<<(BATCH * 7 / 2 + 3) / 4, 256, 0, stream>>>(batch_inputs, eo2, no2, out);
}

// Round 6
// 205.993 us; speedup vs baseline: 3.1363x; 1.0231x over previous
//
#include <hip/hip_runtime.h>
#include <math.h>

#define N_NODES 50000
#define N_EDGES 25000
#define MAX_ARITY 6
#define MAX_DEG 8
#define NFEAT 128
#define NHID 64
#define NEMB 128
#define NHEADS 4
#define BATCH 4096

// padded m-tile counts (16 rows per tile)
#define MT_N 3128   // ceil(50000/128)*8 -> rows padded to 50048

typedef __bf16 bf16x8 __attribute__((ext_vector_type(8)));
typedef __bf16 bf16x4 __attribute__((ext_vector_type(4)));
typedef float f32x4 __attribute__((ext_vector_type(4)));
typedef float f32x2 __attribute__((ext_vector_type(2)));

__device__ __forceinline__ float wave_sum(float v) {
#pragma unroll
    for (int off = 1; off < 64; off <<= 1) v += __shfl_xor(v, off);
    return v;
}
__device__ __forceinline__ float group32_sum(float v) {
#pragma unroll
    for (int off = 1; off < 32; off <<= 1) v += __shfl_xor(v, off);
    return v;
}
__device__ __forceinline__ float group16_sum(float v) {
#pragma unroll
    for (int off = 1; off < 16; off <<= 1) v += __shfl_xor(v, off);
    return v;
}
__device__ __forceinline__ float group8_sum(float v) {
#pragma unroll
    for (int off = 1; off < 8; off <<= 1) v += __shfl_xor(v, off);
    return v;
}
__device__ __forceinline__ float lrelu(float x) { return x >= 0.f ? x : 0.2f * x; }
__device__ __forceinline__ float eluf(float x) { return x > 0.f ? x : expm1f(x); }

// ---- fp8 e4m3 (OCP on gfx950) pack/unpack helpers ----
__device__ __forceinline__ int2 pack_fp8x8(const float* v) {
    int w0 = __builtin_amdgcn_cvt_pk_fp8_f32(v[0], v[1], 0, 0);
    w0 = __builtin_amdgcn_cvt_pk_fp8_f32(v[2], v[3], w0, 1);
    int w1 = __builtin_amdgcn_cvt_pk_fp8_f32(v[4], v[5], 0, 0);
    w1 = __builtin_amdgcn_cvt_pk_fp8_f32(v[6], v[7], w1, 1);
    int2 o;
    o.x = w0;
    o.y = w1;
    return o;
}
__device__ __forceinline__ void unpack_fp8x8(int2 w, float* v) {
    f32x2 a = __builtin_amdgcn_cvt_pk_f32_fp8(w.x, false);
    f32x2 b = __builtin_amdgcn_cvt_pk_f32_fp8(w.x, true);
    f32x2 c = __builtin_amdgcn_cvt_pk_f32_fp8(w.y, false);
    f32x2 d = __builtin_amdgcn_cvt_pk_f32_fp8(w.y, true);
    v[0] = a[0]; v[1] = a[1]; v[2] = b[0]; v[3] = b[1];
    v[4] = c[0]; v[5] = c[1]; v[6] = d[0]; v[7] = d[1];
}
__device__ __forceinline__ unsigned char fp8_of(float x) {
    return (unsigned char)(__builtin_amdgcn_cvt_pk_fp8_f32(x, x, 0, 0) & 0xff);
}

// ---------------------------------------------------------------------------
// PREP mega-kernel: repack(A1n) + bconv(B1n) + bconv(B2n) + wvec1 + wvec2 + c1
// ---------------------------------------------------------------------------
#define PREP_REPACK_BLKS 3128   // MT_N*4*64/256
#define PREP_BCONV1_BLKS 16
#define PREP_BCONV2_BLKS 16
#define PREP_WVEC1_BLKS 2
#define PREP_WVEC2_BLKS 1
#define PREP_C1_BLKS 6250       // N_EDGES/4
#define PREP_TOTAL_BLKS (PREP_REPACK_BLKS + PREP_BCONV1_BLKS + PREP_BCONV2_BLKS + \
                         PREP_WVEC1_BLKS + PREP_WVEC2_BLKS + PREP_C1_BLKS)

__global__ __launch_bounds__(256) void prep_kernel(
    const float* __restrict__ node_embs, const float* __restrict__ edge_embs,
    const float* __restrict__ Wn, const float* __restrict__ We, const float* __restrict__ a1,
    const float* __restrict__ Wn_o, const float* __restrict__ We_o,
    const float* __restrict__ a1_o, __bf16* __restrict__ A1n, __bf16* __restrict__ B1n,
    __bf16* __restrict__ B2n, float* __restrict__ wc1, float* __restrict__ wc2,
    float* __restrict__ c1) {
    int blk = blockIdx.x;
    if (blk < PREP_REPACK_BLKS) {
        int t = blk * 256 + threadIdx.x;
        int lane = t & 63;
        int kt = (t >> 6) & 3;
        int mt = t >> 8;
        int row = mt * 16 + (lane & 15);
        int ks = kt * 32 + (lane >> 4) * 8;
        float v[8];
        if (row < N_NODES) {
            float4 p0 = *reinterpret_cast<const float4*>(node_embs + (size_t)row * 128 + ks);
            float4 p1 = *reinterpret_cast<const float4*>(node_embs + (size_t)row * 128 + ks + 4);
            v[0] = p0.x; v[1] = p0.y; v[2] = p0.z; v[3] = p0.w;
            v[4] = p1.x; v[5] = p1.y; v[6] = p1.z; v[7] = p1.w;
        } else {
#pragma unroll
            for (int j = 0; j < 8; ++j) v[j] = 0.f;
        }
        bf16x8 o;
#pragma unroll
        for (int j = 0; j < 8; ++j) o[j] = (__bf16)v[j];
        reinterpret_cast<bf16x8*>(A1n)[t] = o;
        return;
    }
    blk -= PREP_REPACK_BLKS;
    if (blk < PREP_BCONV1_BLKS) {
        int t = blk * 256 + threadIdx.x;
        int lane = t & 63;
        int nt = (t >> 6) & 15;
        int kt = t >> 10;
        int k0 = kt * 32 + (lane >> 4) * 8;
        int h = nt >> 2;
        int nl = (nt & 3) * 16 + (lane & 15);
        bf16x8 o;
#pragma unroll
        for (int j = 0; j < 8; ++j) o[j] = (__bf16)Wn[(h * NFEAT + k0 + j) * NHID + nl];
        reinterpret_cast<bf16x8*>(B1n)[t] = o;
        return;
    }
    blk -= PREP_BCONV1_BLKS;
    if (blk < PREP_BCONV2_BLKS) {
        int t = blk * 256 + threadIdx.x;
        int lane = t & 63;
        int nt = (t >> 6) & 7;
        int kt = t >> 9;
        int k0 = kt * 32 + (lane >> 4) * 8;
        int n = nt * 16 + (lane & 15);
        bf16x8 o;
#pragma unroll
        for (int j = 0; j < 8; ++j) o[j] = (__bf16)Wn_o[(size_t)(k0 + j) * 128 + n];
        reinterpret_cast<bf16x8*>(B2n)[t] = o;
        return;
    }
    blk -= PREP_BCONV2_BLKS;
    if (blk < PREP_WVEC1_BLKS) {
        int t = blk * 256 + threadIdx.x;
        int h = t >> 7, k = t & 127;
        float s = 0.f;
        for (int j = 0; j < 64; ++j) s += We[(h * NFEAT + k) * NHID + j] * a1[h * 128 + j];
        wc1[t] = s;
        return;
    }
    blk -= PREP_WVEC1_BLKS;
    if (blk < PREP_WVEC2_BLKS) {
        int t = threadIdx.x;
        float s = 0.f;
        for (int j = 0; j < 128; ++j) s += We_o[(size_t)t * 128 + j] * a1_o[j];
        wc2[t] = s;
        return;
    }
    blk -= PREP_WVEC2_BLKS;
    {
        int r = blk * 4 + (threadIdx.x >> 6);
        int lane = threadIdx.x & 63;
        if (r >= N_EDGES) return;
        float x0 = edge_embs[(size_t)r * 128 + lane];
        float x1 = edge_embs[(size_t)r * 128 + 64 + lane];
#pragma unroll
        for (int h = 0; h < 4; ++h) {
            float s = wave_sum(x0 * wc1[h * 128 + lane] + x1 * wc1[h * 128 + 64 + lane]);
            if (lane == 0) c1[r * 4 + h] = s;
        }
    }
}

// ---------------------------------------------------------------------------
// LDS-free MFMA GEMM; C written as fp8 (C8=true) or bf16. MPW = m-tiles/wave.
// ---------------------------------------------------------------------------
template <int KT, int BNF, int DOTMODE, int NDOTV, int MPW, bool C8>
__global__ __launch_bounds__(256) void mgemm_kernel(
    const __bf16* __restrict__ A, const __bf16* __restrict__ B, void* __restrict__ Cout, int M,
    int N, int NTB, const float* __restrict__ vA, int offA, float* __restrict__ outA,
    const float* __restrict__ vB, int offB, float* __restrict__ outB) {
    const int w = threadIdx.x >> 6, l = threadIdx.x & 63;
    const int mtb = blockIdx.y * (4 * MPW) + w * MPW;
    const int nbf = blockIdx.x * BNF;
    f32x4 acc[MPW][BNF];
#pragma unroll
    for (int i = 0; i < MPW; ++i)
#pragma unroll
        for (int j = 0; j < BNF; ++j) acc[i][j] = (f32x4){0.f, 0.f, 0.f, 0.f};
    const bf16x8* Ap = reinterpret_cast<const bf16x8*>(A) + (size_t)mtb * KT * 64 + l;
    const bf16x8* Bp = reinterpret_cast<const bf16x8*>(B) + l;
#pragma unroll
    for (int kt = 0; kt < KT; ++kt) {
        bf16x8 a[MPW];
#pragma unroll
        for (int mi = 0; mi < MPW; ++mi) a[mi] = Ap[((size_t)mi * KT + kt) * 64];
#pragma unroll
        for (int nj = 0; nj < BNF; ++nj) {
            bf16x8 b = Bp[((size_t)kt * NTB + nbf + nj) * 64];
#pragma unroll
            for (int mi = 0; mi < MPW; ++mi)
                acc[mi][nj] = __builtin_amdgcn_mfma_f32_16x16x32_bf16(a[mi], b, acc[mi][nj], 0, 0, 0);
        }
    }
    const int rq = (l >> 4) * 4;
    const int cl = l & 15;
#pragma unroll
    for (int mi = 0; mi < MPW; ++mi) {
        int mbase = (mtb + mi) * 16 + rq;
#pragma unroll
        for (int q = 0; q < 4; ++q) {
            int m = mbase + q;
            if (m < M) {
#pragma unroll
                for (int nj = 0; nj < BNF; ++nj) {
                    if (C8) {
                        ((unsigned char*)Cout)[(size_t)m * N + (nbf + nj) * 16 + cl] =
                            fp8_of(acc[mi][nj][q]);
                    } else {
                        ((__bf16*)Cout)[(size_t)m * N + (nbf + nj) * 16 + cl] =
                            (__bf16)acc[mi][nj][q];
                    }
                }
            }
        }
    }
    if (DOTMODE) {
        float va[BNF], vb[BNF];
        const int vbase = (DOTMODE == 1) ? (nbf >> 2) * 128 : 0;
#pragma unroll
        for (int nj = 0; nj < BNF; ++nj) {
            int col = (DOTMODE == 1) ? ((nbf + nj) & 3) * 16 + cl : (nbf + nj) * 16 + cl;
            va[nj] = vA[vbase + offA + col];
            if (NDOTV >= 2) vb[nj] = vB[vbase + offB + col];
        }
        const int outStride = (DOTMODE == 1) ? 4 : 1;
        const int outOff = (DOTMODE == 1) ? (nbf >> 2) : 0;
#pragma unroll
        for (int mi = 0; mi < MPW; ++mi) {
#pragma unroll
            for (int q = 0; q < 4; ++q) {
                float pA = 0.f, pB = 0.f;
#pragma unroll
                for (int nj = 0; nj < BNF; ++nj) {
                    pA += acc[mi][nj][q] * va[nj];
                    if (NDOTV >= 2) pB += acc[mi][nj][q] * vb[nj];
                }
                pA = group16_sum(pA);
                if (NDOTV >= 2) pB = group16_sum(pB);
                int m = (mtb + mi) * 16 + rq + q;
                if (cl == 0 && m < M) {
                    outA[(size_t)m * outStride + outOff] = pA;
                    if (NDOTV >= 2) outB[(size_t)m * outStride + outOff] = pB;
                }
            }
        }
    }
}

// ---------------------------------------------------------------------------
// Layer-1 EDGE attention: 2 edges/wave, 32 lanes/edge, lane owns 8 feats.
// feat (hn1) is fp8; output eo1 fp8. Gathers prefetched before score compute.
// ---------------------------------------------------------------------------
__global__ __launch_bounds__(256) void attn64e_kernel(
    const int* __restrict__ nbr, const unsigned char* __restrict__ feat,
    const float* __restrict__ sdot, const float* __restrict__ ndot,
    const float* __restrict__ a2v, const float* __restrict__ wc2,
    unsigned char* __restrict__ eo1, float* __restrict__ f1, float* __restrict__ c2, int rows) {
    const int lane = threadIdx.x & 63;
    const int half = lane >> 5, lp = lane & 31;
    const int r = (blockIdx.x * 4 + (threadIdx.x >> 6)) * 2 + half;
    if (r >= rows) return;
    const int h = lp >> 3;
    int id[MAX_ARITY];
    bool val[MAX_ARITY];
#pragma unroll
    for (int a = 0; a < MAX_ARITY; ++a) {
        int v = nbr[r * MAX_ARITY + a];
        val[a] = v > 0;
        id[a] = val[a] ? (v - 1) : 0;
    }
    int2 f8[MAX_ARITY];
    float nd[MAX_ARITY];
#pragma unroll
    for (int a = 0; a < MAX_ARITY; ++a) {
        f8[a] = *reinterpret_cast<const int2*>(feat + (size_t)id[a] * 256 + lp * 8);
        nd[a] = ndot[(size_t)id[a] * 4 + h];
    }
    const float c = sdot[r * 4 + h];
    float wgt[MAX_ARITY];
    float smax = -1e30f;
#pragma unroll
    for (int a = 0; a < MAX_ARITY; ++a) {
        float s = val[a] ? lrelu(c + nd[a]) : -3e30f;
        wgt[a] = s;
        if (val[a]) smax = fmaxf(smax, s);
    }
    float denom = 0.f;
#pragma unroll
    for (int a = 0; a < MAX_ARITY; ++a) {
        float ex = val[a] ? expf(wgt[a] - smax) : 0.f;
        wgt[a] = ex;
        denom += ex;
    }
    float inv = 1.f / denom;
    float acc[8] = {0.f, 0.f, 0.f, 0.f, 0.f, 0.f, 0.f, 0.f};
#pragma unroll
    for (int a = 0; a < MAX_ARITY; ++a) {
        float fv[8];
        unpack_fp8x8(f8[a], fv);
#pragma unroll
        for (int j = 0; j < 8; ++j) acc[j] = fmaf(wgt[a], fv[j], acc[j]);
    }
#pragma unroll
    for (int j = 0; j < 8; ++j) acc[j] *= inv;
    *reinterpret_cast<int2*>(eo1 + (size_t)r * 256 + lp * 8) = pack_fp8x8(acc);
    float p = 0.f;
#pragma unroll
    for (int j = 0; j < 8; ++j) p += acc[j] * a2v[h * 128 + 64 + (lp & 7) * 8 + j];
    p = group8_sum(p);
    if ((lp & 7) == 0) f1[r * 4 + h] = p;
    float p2 = 0.f;
#pragma unroll
    for (int j = 0; j < 8; ++j) p2 += eluf(acc[j]) * wc2[lp * 8 + j];
    p2 = group32_sum(p2);
    if (lp == 0) c2[r] = p2;
}

// ---------------------------------------------------------------------------
// Layer-1 NODE attention: 2 nodes/wave; feat (eo1) fp8; writes elu(out)
// directly as bf16 A-fragments for GEMM2 (KT=8).
// ---------------------------------------------------------------------------
__global__ __launch_bounds__(256) void attn64n_kernel(const int* __restrict__ nbr,
                                                      const unsigned char* __restrict__ feat,
                                                      const float* __restrict__ sdot,
                                                      const float* __restrict__ ndot,
                                                      __bf16* __restrict__ Afrag, int rows,
                                                      int rowsPad) {
    const int lane = threadIdx.x & 63;
    const int half = lane >> 5, lp = lane & 31;
    const int r = (blockIdx.x * 4 + (threadIdx.x >> 6)) * 2 + half;
    if (r >= rowsPad) return;
    const int rr = r & 15, mt = r >> 4;
    const int kt = lp >> 2, g = lp & 3;
    __bf16* dptr = Afrag + ((((size_t)mt * 8 + kt) * 64 + g * 16 + rr) << 3);
    if (r >= rows) {
        bf16x8 z;
#pragma unroll
        for (int j = 0; j < 8; ++j) z[j] = (__bf16)0.f;
        *reinterpret_cast<bf16x8*>(dptr) = z;
        return;
    }
    const int h = lp >> 3;
    int id[MAX_DEG];
    bool val[MAX_DEG];
#pragma unroll
    for (int a = 0; a < MAX_DEG; ++a) {
        int v = nbr[r * MAX_DEG + a];
        val[a] = v > 0;
        id[a] = val[a] ? (v - 1) : 0;
    }
    int2 f8[MAX_DEG];
    float nd[MAX_DEG];
#pragma unroll
    for (int a = 0; a < MAX_DEG; ++a) {
        f8[a] = *reinterpret_cast<const int2*>(feat + (size_t)id[a] * 256 + lp * 8);
        nd[a] = ndot[(size_t)id[a] * 4 + h];
    }
    const float c = sdot[r * 4 + h];
    float wgt[MAX_DEG];
    float smax = -1e30f;
#pragma unroll
    for (int a = 0; a < MAX_DEG; ++a) {
        float s = val[a] ? lrelu(c + nd[a]) : -3e30f;
        wgt[a] = s;
        if (val[a]) smax = fmaxf(smax, s);
    }
    float denom = 0.f;
#pragma unroll
    for (int a = 0; a < MAX_DEG; ++a) {
        float ex = val[a] ? expf(wgt[a] - smax) : 0.f;
        wgt[a] = ex;
        denom += ex;
    }
    float inv = 1.f / denom;
    float acc[8] = {0.f, 0.f, 0.f, 0.f, 0.f, 0.f, 0.f, 0.f};
#pragma unroll
    for (int a = 0; a < MAX_DEG; ++a) {
        float fv[8];
        unpack_fp8x8(f8[a], fv);
#pragma unroll
        for (int j = 0; j < 8; ++j) acc[j] = fmaf(wgt[a], fv[j], acc[j]);
    }
    bf16x8 o;
#pragma unroll
    for (int j = 0; j < 8; ++j) o[j] = (__bf16)eluf(acc[j] * inv);
    *reinterpret_cast<bf16x8*>(dptr) = o;
}

// ---------------------------------------------------------------------------
// Layer-2 attention: 4 rows/wave; 16 lanes/row own 8 feats; prefetched (bf16).
// ---------------------------------------------------------------------------
template <int NNBR, bool DOT>
__global__ __launch_bounds__(256) void attn128_kernel(const int* __restrict__ nbr,
                                                      const __bf16* __restrict__ feat,
                                                      const float* __restrict__ sdot,
                                                      const float* __restrict__ ndot,
                                                      const float* __restrict__ fvec,
                                                      __bf16* __restrict__ outF,
                                                      float* __restrict__ outDot, int rows) {
    const int lane = threadIdx.x & 63;
    const int qt = lane >> 4, lq = lane & 15;
    const int r = (blockIdx.x * 4 + (threadIdx.x >> 6)) * 4 + qt;
    if (r >= rows) return;
    int id[NNBR];
    bool val[NNBR];
#pragma unroll
    for (int a = 0; a < NNBR; ++a) {
        int v = nbr[r * NNBR + a];
        val[a] = v > 0;
        id[a] = val[a] ? (v - 1) : 0;
    }
    bf16x8 f8[NNBR];
    float nd[NNBR];
#pragma unroll
    for (int a = 0; a < NNBR; ++a) {
        f8[a] = *reinterpret_cast<const bf16x8*>(feat + (size_t)id[a] * 128 + lq * 8);
        nd[a] = ndot[id[a]];
    }
    const float c = sdot[r];
    float wgt[NNBR];
    float smax = -1e30f;
#pragma unroll
    for (int a = 0; a < NNBR; ++a) {
        float s = val[a] ? lrelu(c + nd[a]) : -3e30f;
        wgt[a] = s;
        if (val[a]) smax = fmaxf(smax, s);
    }
    float denom = 0.f;
#pragma unroll
    for (int a = 0; a < NNBR; ++a) {
        float ex = val[a] ? expf(wgt[a] - smax) : 0.f;
        wgt[a] = ex;
        denom += ex;
    }
    float inv = 1.f / denom;
    float acc[8] = {0.f, 0.f, 0.f, 0.f, 0.f, 0.f, 0.f, 0.f};
#pragma unroll
    for (int a = 0; a < NNBR; ++a)
#pragma unroll
        for (int j = 0; j < 8; ++j) acc[j] = fmaf(wgt[a], (float)f8[a][j], acc[j]);
    bf16x8 o;
#pragma unroll
    for (int j = 0; j < 8; ++j) {
        acc[j] *= inv;
        o[j] = (__bf16)acc[j];
    }
    *reinterpret_cast<bf16x8*>(outF + (size_t)r * 128 + lq * 8) = o;
    if (DOT) {
        float p = 0.f;
#pragma unroll
        for (int j = 0; j < 8; ++j) p += acc[j] * fvec[128 + lq * 8 + j];
        p = group16_sum(p);
        if (lq == 0) outDot[r] = p;
    }
}

// ---------------------------------------------------------------------------
// Batch gather: 2 (b,slot) pairs per wave; 32 lanes own 4 feats each.
// ---------------------------------------------------------------------------
__global__ __launch_bounds__(256) void batch_kernel(const int* __restrict__ bi,
                                                    const __bf16* __restrict__ eo2,
                                                    const __bf16* __restrict__ no2,
                                                    float* __restrict__ out) {
    const int lane = threadIdx.x & 63;
    const int half = lane >> 5, lp = lane & 31;
    const int gw = (blockIdx.x * 4 + (threadIdx.x >> 6)) * 2 + half;
    if (gw >= BATCH * 7) return;
    int b = gw / 7, s = gw % 7;
    int last_nz = -1;
#pragma unroll
    for (int j = 0; j < 7; ++j)
        if (bi[b * 7 + j] != 0) last_nz = j;
    float4 v;
    if (s == 0) {
        int e = bi[b * 7] - 1;
        bf16x4 t = *reinterpret_cast<const bf16x4*>(eo2 + (size_t)e * 128 + lp * 4);
        v = make_float4(eluf((float)t[0]), eluf((float)t[1]), eluf((float)t[2]),
                        eluf((float)t[3]));
    } else if (s <= last_nz) {
        int nid = bi[b * 7 + s] - 1;
        if (nid < 0) nid += N_NODES;
        bf16x4 t = *reinterpret_cast<const bf16x4*>(no2 + (size_t)nid * 128 + lp * 4);
        v = make_float4(eluf((float)t[0]), eluf((float)t[1]), eluf((float)t[2]),
                        eluf((float)t[3]));
    } else {
        v = make_float4(1.f, 1.f, 1.f, 1.f);
    }
    *reinterpret_cast<float4*>(out + (size_t)b * 896 + s * 128 + lp * 4) = v;
}

// ---------------------------------------------------------------------------
extern "C" void kernel_launch(void* const* d_in, const int* in_sizes, int n_in,
                              void* d_out, int out_size, void* d_ws, size_t ws_size,
                              hipStream_t stream) {
    const int* batch_inputs = (const int*)d_in[0];
    const int* edge_list = (const int*)d_in[1];
    const int* node_list = (const int*)d_in[2];
    const float* node_embs = (const float*)d_in[3];
    const float* edge_embs = (const float*)d_in[4];
    const float* Wn = (const float*)d_in[5];
    const float* We = (const float*)d_in[6];
    const float* a1 = (const float*)d_in[7];
    const float* a2 = (const float*)d_in[8];
    const float* Wn_o = (const float*)d_in[9];
    const float* We_o = (const float*)d_in[10];
    const float* a1_o = (const float*)d_in[11];
    const float* a2_o = (const float*)d_in[12];
    float* out = (float*)d_out;
    char* ws = (char*)d_ws;

    // ---- workspace layout (bytes) ----
    __bf16* A1n = (__bf16*)(ws);                      // 12,812,288
    __bf16* B1n = (__bf16*)(ws + 12812288);           // 65,536
    __bf16* B2n = (__bf16*)(ws + 12877824);           // 65,536
    float* wc1 = (float*)(ws + 12943360);             // 2,048
    float* wc2 = (float*)(ws + 12945408);             // 1,024
    float* c1 = (float*)(ws + 12946432);              // 400,000
    float* d1 = (float*)(ws + 13346432);              // 800,000
    float* g1v = (float*)(ws + 14146432);             // 800,000
    float* f1 = (float*)(ws + 14946432);              // 400,000
    float* c2 = (float*)(ws + 15346432);              // 100,000
    float* d2 = (float*)(ws + 15446432);              // 200,000
    float* g2v = (float*)(ws + 15646432);             // 200,000
    float* f2 = (float*)(ws + 15846432);              // 100,000
    unsigned char* hn1 = (unsigned char*)(ws + 16000000);  // 12,800,000 (50000x256 fp8)
    __bf16* A2n = (__bf16*)(ws + 28800000);           // 25,624,576
    __bf16* hn2 = (__bf16*)(ws + 54424576);           // 12,800,000 (50000x128 bf16)
    unsigned char* eo1 = (unsigned char*)(ws + 67224576);  // 6,400,000 (25000x256 fp8)
    __bf16* no2 = (__bf16*)(ws + 67224576);           // overlays eo1 (dead after attn64n)
    __bf16* eo2 = (__bf16*)(ws + 80024576);           // 6,400,000 -> ends 86,424,576

    // 1) merged prep
    prep_kernel<<<PREP_TOTAL_BLKS, 256, 0, stream>>>(node_embs, edge_embs, Wn, We, a1, Wn_o,
                                                     We_o, a1_o, A1n, B1n, B2n, wc1, wc2, c1);

    // 2) G1n: hn1(fp8) = node_embs @ Wn  (+ d1, g1v)   [MPW=2]
    {
        dim3 g(4, MT_N / 8);
        mgemm_kernel<4, 4, 1, 2, 2, true><<<g, 256, 0, stream>>>(
            A1n, B1n, hn1, N_NODES, 256, 16, a1, 64, d1, a2, 0, g1v);
    }
    // 3) layer-1 edge attention -> eo1(fp8), f1, c2
    attn64e_kernel<<<(N_EDGES / 2 + 3) / 4, 256, 0, stream>>>(edge_list, hn1, c1, d1, a2, wc2,
                                                              eo1, f1, c2, N_EDGES);
    // 4) layer-1 node attention -> A2n (elu'd bf16 frags)
    attn64n_kernel<<<(MT_N * 16 / 2 + 3) / 4, 256, 0, stream>>>(node_list, eo1, g1v, f1, A2n,
                                                                N_NODES, MT_N * 16);
    // 5) G2n: hn2(bf16) = no1 @ Wn_o (+ d2, g2v)   [MPW=1 -> 782 blocks]
    {
        dim3 g(1, MT_N / 4);
        mgemm_kernel<8, 8, 2, 2, 1, false><<<g, 256, 0, stream>>>(
            A2n, B2n, hn2, N_NODES, 128, 8, a1_o, 128, d2, a2_o, 0, g2v);
    }
    // 6) layer-2 edge attention -> eo2(bf16), f2
    attn128_kernel<MAX_ARITY, true><<<(N_EDGES / 4 + 3) / 4, 256, 0, stream>>>(
        edge_list, hn2, c2, d2, a2_o, eo2, f2, N_EDGES);
    // 7) layer-2 node attention -> no2(bf16)
    attn128_kernel<MAX_DEG, false><<<(N_NODES / 4 + 3) / 4, 256, 0, stream>>>(
        node_list, eo2, g2v, f2, nullptr, no2, nullptr, N_NODES);
    // 8) batch gather
    batch_kernel<<<(BATCH * 7 / 2 + 3) / 4, 256, 0, stream>>>(batch_inputs, eo2, no2, out);
}